// Round 2
// baseline (41334.879 us; speedup 1.0000x reference)
//
#include <hip/hip_runtime.h>

// ---------------------------------------------------------------------------
// WeatherModel: ConvLSTM encoder-decoder with input + temporal attention.
// B=8, T=10, D=10, H=W=128, fp32 (no fp32 MFMA on CDNA4 -> vector ALU).
// Round 2: adaptive batch tiling (ws_size unknown; round-1 evidence says
// ws < 790 MB). Compounded input attention stored as running product A
// instead of materializing reweighted xx.
// ---------------------------------------------------------------------------

#define PX 16384L   // 128*128
#define T_ 10
#define D_ 10

constexpr int CI = 4;   // input channels staged in LDS per sync

__device__ __forceinline__ float sigmoidf_(float x) { return 1.f / (1.f + expf(-x)); }

// ---------------- generic 3x3 SAME conv, concat of up to 3 inputs ----------
// blockIdx.z = f * nb + b  (f = feature/timestep fold, b = local batch)
// input i: channels c_i, batch stride bs_i, channel stride cst_i, f stride fs_i
// optional per-pixel scale on input0's channels: sc[b*sbs + ci*scst + f*sfs + pix]
template<int COPB, bool TANH>
__global__ __launch_bounds__(256)
void conv3x3_k(const float* __restrict__ in0, int c0, long bs0, long cst0, long fs0,
               const float* __restrict__ in1, int c1, long bs1, long cst1, long fs1,
               const float* __restrict__ in2, int c2, long bs2, long cst2, long fs2,
               const float* __restrict__ sc, long sbs, long scst, long sfs,
               const float* __restrict__ w, const float* __restrict__ bias,
               float* __restrict__ out, long obs, long ofs, int nb)
{
    __shared__ float lds[CI][18][18];
    const int tid = threadIdx.x;
    const int tx = tid & 15, ty = tid >> 4;
    const int tileX = (blockIdx.x & 7) << 4, tileY = (blockIdx.x >> 3) << 4;
    const int z = blockIdx.z;
    const int b = z % nb, f = z / nb;
    const int cin = c0 + c1 + c2;
    const int co0 = blockIdx.y * COPB;
    float acc[COPB];
#pragma unroll
    for (int j = 0; j < COPB; j++) acc[j] = 0.f;

    for (int cb = 0; cb < cin; cb += CI) {
        const int cmax = min(CI, cin - cb);
        for (int idx = tid; idx < cmax * 324; idx += 256) {
            const int cl = idx / 324;
            const int rem = idx - cl * 324;
            const int ly = rem / 18, lx = rem - (rem / 18) * 18;
            const int gy = tileY + ly - 1, gx = tileX + lx - 1;
            const int ci = cb + cl;
            float v = 0.f;
            if ((unsigned)gy < 128u && (unsigned)gx < 128u) {
                const int pix = gy * 128 + gx;
                const float* p;
                long soff = -1;
                if (ci < c0) {
                    p = in0 + (long)b * bs0 + (long)ci * cst0 + (long)f * fs0;
                    if (sc) soff = (long)b * sbs + (long)ci * scst + (long)f * sfs;
                } else if (ci < c0 + c1) {
                    p = in1 + (long)b * bs1 + (long)(ci - c0) * cst1 + (long)f * fs1;
                } else {
                    p = in2 + (long)b * bs2 + (long)(ci - c0 - c1) * cst2 + (long)f * fs2;
                }
                v = p[pix];
                if (soff >= 0) v *= sc[soff + pix];
            }
            lds[cl][ly][lx] = v;
        }
        __syncthreads();
        for (int cl = 0; cl < cmax; cl++) {
            float r[9];
#pragma unroll
            for (int dy = 0; dy < 3; dy++)
#pragma unroll
                for (int dx = 0; dx < 3; dx++)
                    r[dy * 3 + dx] = lds[cl][ty + dy][tx + dx];
            const int ci = cb + cl;
#pragma unroll
            for (int j = 0; j < COPB; j++) {
                const float* wp = w + ((long)(co0 + j) * cin + ci) * 9;
                float a = acc[j];
#pragma unroll
                for (int q = 0; q < 9; q++) a = fmaf(wp[q], r[q], a);
                acc[j] = a;
            }
        }
        __syncthreads();
    }
    const long opix = (long)(tileY + ty) * 128 + tileX + tx;
#pragma unroll
    for (int j = 0; j < COPB; j++) {
        float v = acc[j] + bias[co0 + j];
        if (TANH) v = tanhf(v);
        out[(long)b * obs + (long)(co0 + j) * PX + (long)f * ofs + opix] = v;
    }
}

// ---------------- fused conv3x3 + ConvLSTM gates ---------------------------
// z = conv(concat[in0, in1]) + bias  (4*hidden out channels, i|f|o|g blocks)
// c2 = sig(f)*cprev + sig(i)*tanh(g); h2 = sig(o)*tanh(c2)
template<int HCPB>
__global__ __launch_bounds__(256)
void conv_lstm_k(const float* __restrict__ in0, int c0, long bs0, long cst0,
                 const float* __restrict__ in1, int c1, long bs1, long cst1,
                 const float* __restrict__ sc, long sbs, long scst,
                 const float* __restrict__ w, const float* __restrict__ bias, int hidden,
                 const float* __restrict__ cprev, long cpbs,
                 float* __restrict__ hout, long hobs,
                 float* __restrict__ cout_, long cobs,
                 float* __restrict__ hout2, long ho2bs)
{
    __shared__ float lds[CI][18][18];
    const int tid = threadIdx.x;
    const int tx = tid & 15, ty = tid >> 4;
    const int tileX = (blockIdx.x & 7) << 4, tileY = (blockIdx.x >> 3) << 4;
    const int b = blockIdx.z;
    const int cin = c0 + c1;
    const int hc0 = blockIdx.y * HCPB;
    float acc[HCPB][4];
#pragma unroll
    for (int j = 0; j < HCPB; j++)
#pragma unroll
        for (int g = 0; g < 4; g++) acc[j][g] = 0.f;

    for (int cb = 0; cb < cin; cb += CI) {
        const int cmax = min(CI, cin - cb);
        for (int idx = tid; idx < cmax * 324; idx += 256) {
            const int cl = idx / 324;
            const int rem = idx - cl * 324;
            const int ly = rem / 18, lx = rem - (rem / 18) * 18;
            const int gy = tileY + ly - 1, gx = tileX + lx - 1;
            const int ci = cb + cl;
            float v = 0.f;
            if ((unsigned)gy < 128u && (unsigned)gx < 128u) {
                const int pix = gy * 128 + gx;
                const float* p;
                long soff = -1;
                if (ci < c0) {
                    p = in0 + (long)b * bs0 + (long)ci * cst0;
                    if (sc) soff = (long)b * sbs + (long)ci * scst;
                } else {
                    p = in1 + (long)b * bs1 + (long)(ci - c0) * cst1;
                }
                v = p[pix];
                if (soff >= 0) v *= sc[soff + pix];
            }
            lds[cl][ly][lx] = v;
        }
        __syncthreads();
        for (int cl = 0; cl < cmax; cl++) {
            float r[9];
#pragma unroll
            for (int dy = 0; dy < 3; dy++)
#pragma unroll
                for (int dx = 0; dx < 3; dx++)
                    r[dy * 3 + dx] = lds[cl][ty + dy][tx + dx];
            const int ci = cb + cl;
#pragma unroll
            for (int j = 0; j < HCPB; j++)
#pragma unroll
                for (int g = 0; g < 4; g++) {
                    const float* wp = w + ((long)(g * hidden + hc0 + j) * cin + ci) * 9;
                    float a = acc[j][g];
#pragma unroll
                    for (int q = 0; q < 9; q++) a = fmaf(wp[q], r[q], a);
                    acc[j][g] = a;
                }
        }
        __syncthreads();
    }
    const long opix = (long)(tileY + ty) * 128 + tileX + tx;
#pragma unroll
    for (int j = 0; j < HCPB; j++) {
        const int hc = hc0 + j;
        const float i_ = sigmoidf_(acc[j][0] + bias[hc]);
        const float f_ = sigmoidf_(acc[j][1] + bias[hidden + hc]);
        const float o_ = sigmoidf_(acc[j][2] + bias[2 * hidden + hc]);
        const float g_ = tanhf(acc[j][3] + bias[3 * hidden + hc]);
        const float cp = cprev[(long)b * cpbs + (long)hc * PX + opix];
        const float c2 = f_ * cp + i_ * g_;
        const float h2 = o_ * tanhf(c2);
        hout[(long)b * hobs + (long)hc * PX + opix] = h2;
        cout_[(long)b * cobs + (long)hc * PX + opix] = c2;
        if (hout2) hout2[(long)b * ho2bs + (long)hc * PX + opix] = h2;
    }
}

// ---------------- softmax over 10 slots, layout (nb, 10, P) ----------------
__global__ __launch_bounds__(256)
void softmax_k(float* __restrict__ s, int nb)
{
    const long idx = (long)blockIdx.x * 256 + threadIdx.x;
    if (idx >= (long)nb * PX) return;
    const long b = idx >> 14, p = idx & 16383;
    float* base = s + b * 10 * PX + p;
    float v[10];
    float m = -1e30f;
#pragma unroll
    for (int t = 0; t < 10; t++) { v[t] = base[t * PX]; m = fmaxf(m, v[t]); }
    float sum = 0.f;
#pragma unroll
    for (int t = 0; t < 10; t++) { v[t] = expf(v[t] - m); sum += v[t]; }
    const float r = 1.f / sum;
#pragma unroll
    for (int t = 0; t < 10; t++) base[t * PX] = v[t] * r;
}

// ---------------- A *= alpha (elementwise, same layout) --------------------
__global__ __launch_bounds__(256)
void aupdate_k(float* __restrict__ A, const float* __restrict__ alpha, long n)
{
    const long idx = (long)blockIdx.x * 256 + threadIdx.x;
    if (idx < n) A[idx] *= alpha[idx];
}

__global__ __launch_bounds__(256)
void ones_k(float* __restrict__ A, long n)
{
    const long idx = (long)blockIdx.x * 256 + threadIdx.x;
    if (idx < n) A[idx] = 1.f;
}

// ------ temporal weighted sum: out[b,ch,p] = sum_t beta[b,t,p]*hb[t,b,ch,p] -
__global__ __launch_bounds__(256)
void wsum_k(const float* __restrict__ beta, const float* __restrict__ hb,
            float* __restrict__ out, int nb, long slot1)
{
    const long idx = (long)blockIdx.x * 256 + threadIdx.x;
    if (idx >= (long)nb * 64 * PX) return;
    const long p = idx & 16383;
    const long b = idx >> 20;          // idx / (64*PX)
    float a = 0.f;
#pragma unroll
    for (int t = 0; t < 10; t++)
        a += beta[(b * 10 + t) * PX + p] * hb[t * slot1 + idx];
    out[idx] = a;
}

// ---------------------------------------------------------------------------
extern "C" void kernel_launch(void* const* d_in, const int* in_sizes, int n_in,
                              void* d_out, int out_size, void* d_ws, size_t ws_size,
                              hipStream_t stream)
{
    const float* x      = (const float*)d_in[0];
    const float* h0     = (const float*)d_in[1];
    const float* c0     = (const float*)d_in[2];
    const float* h1     = (const float*)d_in[3];
    const float* c1     = (const float*)d_in[4];
    const float* w_enc0 = (const float*)d_in[5];
    const float* b_enc0 = (const float*)d_in[6];
    const float* w_enc1 = (const float*)d_in[7];
    const float* b_enc1 = (const float*)d_in[8];
    const float* w_dec0 = (const float*)d_in[9];
    const float* b_dec0 = (const float*)d_in[10];
    const float* w_dec1 = (const float*)d_in[11];
    const float* b_dec1 = (const float*)d_in[12];
    const float* wa1 = (const float*)d_in[13];
    const float* ba1 = (const float*)d_in[14];
    const float* wa2 = (const float*)d_in[15];
    const float* ba2 = (const float*)d_in[16];
    const float* wt1 = (const float*)d_in[17];
    const float* bt1 = (const float*)d_in[18];
    const float* wt2 = (const float*)d_in[19];
    const float* bt2 = (const float*)d_in[20];
    float* out = (float*)d_out;

    // ---- choose batch tile nb: need = 1640 * PX * nb floats ----
    int nb = 0;
    for (int cand = 8; cand >= 1; cand >>= 1) {
        const size_t need = (size_t)1640 * PX * cand * sizeof(float);
        if (need <= ws_size) { nb = cand; break; }
    }
    if (nb == 0) return;   // ws < 107.5 MB: signal via zero output

    // ---- workspace layout (floats), per batch-group of nb ----
    float* ws = (float*)d_ws;
    const long slot0 = (long)nb * PX;          // hs0/cs0 per-t slot
    const long slot1 = (long)nb * 64 * PX;     // hs1/cs1 per-t slot
    float* hs0   = ws;                          // 10 * slot0
    float* cs0   = hs0 + 10 * slot0;            // 10 * slot0
    float* hs1   = cs0 + 10 * slot0;            // 10 * slot1
    float* cs1   = hs1 + 10 * slot1;            // 10 * slot1
    float* A     = cs1 + 10 * slot1;            // nb * 10 * PX
    float* score = A + (long)nb * 10 * PX;      // nb * 10 * PX
    float* z1    = score + (long)nb * 10 * PX;  // nb * 10 * 32 * PX (f-folded)
    float* aht   = z1;                          // alias: z1 dead when aht live

    const dim3 blk(256);
    const long TDP = (long)T_ * D_ * PX;

    for (int b0 = 0; b0 < 8; b0 += nb) {
        const float* xb  = x  + (long)b0 * TDP;
        const float* h0b = h0 + (long)b0 * PX;
        const float* c0b = c0 + (long)b0 * PX;
        const float* h1b = h1 + (long)b0 * 64 * PX;
        const float* c1b = c1 + (long)b0 * 64 * PX;
        float* outb = out + (long)b0 * 5 * PX;

        ones_k<<<(int)((long)nb * 10 * PX / 256), blk, 0, stream>>>(A, (long)nb * 10 * PX);

        // ============ encoder layer 0 (compounding input attention) ============
        for (int t = 0; t < 10; t++) {
            const float* hprev = (t == 0) ? h0b : hs0 + (long)(t - 1) * slot0;
            const float* cprev = (t == 0) ? c0b : cs0 + (long)(t - 1) * slot0;
            // attention score per feature k (folded into grid.z):
            // input = [x[:, :, k] * A[:, k]  (T=10 ch), hprev (1), cprev (1)]
            conv3x3_k<8, true><<<dim3(64, 4, 10 * nb), blk, 0, stream>>>(
                xb, 10, TDP, (long)D_ * PX, PX,      // ch = t-axis, f = k
                hprev, 1, PX, PX, 0,
                cprev, 1, PX, PX, 0,
                A, 10 * PX, 0, PX,                   // scale A[b,k,p], k = f
                wa1, ba1, z1, 32 * PX, (long)nb * 32 * PX, nb);
            conv3x3_k<1, false><<<dim3(64, 1, 10 * nb), blk, 0, stream>>>(
                z1, 32, 32 * PX, PX, (long)nb * 32 * PX,
                nullptr, 0, 0, 0, 0, nullptr, 0, 0, 0, 0,
                nullptr, 0, 0, 0,
                wa2, ba2, score, 10 * PX, PX, nb);
            softmax_k<<<nb * 64, blk, 0, stream>>>(score, nb);
            aupdate_k<<<(int)((long)nb * 10 * PX / 256), blk, 0, stream>>>(
                A, score, (long)nb * 10 * PX);
            // LSTM: in = [x[:, t] * A  (D=10 ch), hprev (1)], hidden = 1
            conv_lstm_k<1><<<dim3(64, 1, nb), blk, 0, stream>>>(
                xb + (long)t * D_ * PX, 10, TDP, PX,
                hprev, 1, PX, PX,
                A, 10 * PX, PX,                      // scale A[b,k,p], k = ch
                w_enc0, b_enc0, 1,
                cprev, PX,
                hs0 + (long)t * slot0, PX,
                cs0 + (long)t * slot0, PX,
                (float*)nullptr, 0);
        }

        // ============ encoder layer 1 ============
        for (int t = 0; t < 10; t++) {
            const float* hprev = (t == 0) ? h1b : hs1 + (long)(t - 1) * slot1;
            const float* cprev = (t == 0) ? c1b : cs1 + (long)(t - 1) * slot1;
            conv_lstm_k<2><<<dim3(64, 32, nb), blk, 0, stream>>>(
                hs0 + (long)t * slot0, 1, PX, PX,
                hprev, 64, 64 * PX, PX,
                nullptr, 0, 0,
                w_enc1, b_enc1, 64,
                cprev, 64 * PX,
                hs1 + (long)t * slot1, 64 * PX,
                cs1 + (long)t * slot1, 64 * PX,
                (float*)nullptr, 0);
        }

        // ============ decoder (5 steps) ============
        // hb0/cb0 ring = hs1/cs1 slots; hb1/cb1 ring = hs0/cs0 slots.
        // softmax + weighted sum are slot-order-independent.
        for (int s = 0; s < 5; s++) {
            const float* yptr; long ybs;
            if (s == 0) { yptr = xb + 9L * D_ * PX; ybs = TDP; }      // x[:, -1, 0]
            else        { yptr = hs0 + (long)(s - 1) * slot0; ybs = PX; }
            // temporal attention scores, t folded into grid.z
            conv3x3_k<8, true><<<dim3(64, 4, 10 * nb), blk, 0, stream>>>(
                yptr, 1, ybs, PX, 0,
                hs1, 64, 64 * PX, PX, slot1,
                cs1, 64, 64 * PX, PX, slot1,
                nullptr, 0, 0, 0,
                wt1, bt1, z1, 32 * PX, (long)nb * 32 * PX, nb);
            conv3x3_k<1, false><<<dim3(64, 1, 10 * nb), blk, 0, stream>>>(
                z1, 32, 32 * PX, PX, (long)nb * 32 * PX,
                nullptr, 0, 0, 0, 0, nullptr, 0, 0, 0, 0,
                nullptr, 0, 0, 0,
                wt2, bt2, score, 10 * PX, PX, nb);
            softmax_k<<<nb * 64, blk, 0, stream>>>(score, nb);
            wsum_k<<<(int)((long)nb * 64 * PX / 256), blk, 0, stream>>>(
                score, hs1, aht, nb, slot1);

            const int sl_new = s % 10;          // overwrites oldest slot
            const int sl_last = (s + 9) % 10;   // most recent slot
            // decoder LSTM 0: in = [y (1), attn-sum (64)], c = cb0[:,-1]
            conv_lstm_k<2><<<dim3(64, 32, nb), blk, 0, stream>>>(
                yptr, 1, ybs, PX,
                aht, 64, 64 * PX, PX,
                nullptr, 0, 0,
                w_dec0, b_dec0, 64,
                cs1 + (long)sl_last * slot1, 64 * PX,
                hs1 + (long)sl_new * slot1, 64 * PX,
                cs1 + (long)sl_new * slot1, 64 * PX,
                (float*)nullptr, 0);
            // decoder LSTM 1: in = [ht (64), hb1[:,-1] (1)], hidden = 1
            conv_lstm_k<1><<<dim3(64, 1, nb), blk, 0, stream>>>(
                hs1 + (long)sl_new * slot1, 64, 64 * PX, PX,
                hs0 + (long)sl_last * slot0, 1, PX, PX,
                nullptr, 0, 0,
                w_dec1, b_dec1, 1,
                cs0 + (long)sl_last * slot0, PX,
                hs0 + (long)sl_new * slot0, PX,
                cs0 + (long)sl_new * slot0, PX,
                outb + (long)s * PX, 5 * PX);
        }
    }
}

// Round 3
// 30043.350 us; speedup vs baseline: 1.3758x; 1.3758x over previous
//
#include <hip/hip_runtime.h>

// ---------------------------------------------------------------------------
// WeatherModel: ConvLSTM encoder-decoder with input + temporal attention.
// B=8, T=10, D=10, H=W=128, fp32 (no fp32 MFMA on CDNA4 -> vector ALU).
// Round 3: (a) decoder attention Zpart caching (only 1 ring slot changes per
// decoder step -> cache conv_hc preactivations), (b) 32x32-tile convs with
// 4x1-pixel strips per thread (halves LDS-read issue per FLOP), (c) fused
// softmax+A-update. Adaptive batch tiling kept (ws_size unknown).
// ---------------------------------------------------------------------------

#define PX 16384L   // 128*128
#define T_ 10
#define D_ 10

constexpr int CI = 4;   // input channels staged in LDS per sync

__device__ __forceinline__ float sigmoidf_(float x) { return 1.f / (1.f + expf(-x)); }

// ---------------- generic 3x3 SAME conv, concat of up to 3 inputs ----------
// 32x32 output tile, 256 threads, each thread a 4x1 vertical strip.
// blockIdx.z = f * nb + b. wcin = weight channel stride (usually cin; for the
// Zpart conv it is 129 while cin=128, skipping the y channel).
template<int COPB, bool TANH>
__global__ __launch_bounds__(256)
void conv3x3_k(const float* __restrict__ in0, int c0, long bs0, long cst0, long fs0,
               const float* __restrict__ in1, int c1, long bs1, long cst1, long fs1,
               const float* __restrict__ in2, int c2, long bs2, long cst2, long fs2,
               const float* __restrict__ sc, long sbs, long scst, long sfs,
               const float* __restrict__ w, int wcin, const float* __restrict__ bias,
               float* __restrict__ out, long obs, long ofs, int nb)
{
    __shared__ float lds[CI][1156];           // 34x34 halo per channel
    const int tid = threadIdx.x;
    const int tx = tid & 31, r0 = (tid >> 5) << 2;
    const int tileX = (blockIdx.x & 3) << 5, tileY = (blockIdx.x >> 2) << 5;
    const int z = blockIdx.z;
    const int b = z % nb, f = z / nb;
    const int cin = c0 + c1 + c2;
    const int co0 = blockIdx.y * COPB;
    float acc[COPB * 4];
#pragma unroll
    for (int j = 0; j < COPB * 4; j++) acc[j] = 0.f;

    for (int cb = 0; cb < cin; cb += CI) {
        const int cmax = min(CI, cin - cb);
        for (int cl = 0; cl < cmax; cl++) {
            const int ci = cb + cl;
            const float* p; const float* sp = nullptr;
            if (ci < c0) {
                p = in0 + (long)b * bs0 + (long)ci * cst0 + (long)f * fs0;
                if (sc) sp = sc + (long)b * sbs + (long)ci * scst + (long)f * sfs;
            } else if (ci < c0 + c1) {
                p = in1 + (long)b * bs1 + (long)(ci - c0) * cst1 + (long)f * fs1;
            } else {
                p = in2 + (long)b * bs2 + (long)(ci - c0 - c1) * cst2 + (long)f * fs2;
            }
            for (int idx = tid; idx < 1156; idx += 256) {
                const int r = idx / 34, cc = idx - r * 34;
                const int gy = tileY + r - 1, gx = tileX + cc - 1;
                float v = 0.f;
                if ((unsigned)gy < 128u && (unsigned)gx < 128u) {
                    const int pix = gy * 128 + gx;
                    v = p[pix];
                    if (sp) v *= sp[pix];
                }
                lds[cl][idx] = v;
            }
        }
        __syncthreads();
        for (int cl = 0; cl < cmax; cl++) {
            float win[6][3];
#pragma unroll
            for (int dy = 0; dy < 6; dy++)
#pragma unroll
                for (int dx = 0; dx < 3; dx++)
                    win[dy][dx] = lds[cl][(r0 + dy) * 34 + tx + dx];
            const int ci = cb + cl;
#pragma unroll
            for (int j = 0; j < COPB; j++) {
                const float* wp = w + ((long)(co0 + j) * wcin + ci) * 9;
#pragma unroll
                for (int rr = 0; rr < 4; rr++) {
                    float a = acc[j * 4 + rr];
#pragma unroll
                    for (int ky = 0; ky < 3; ky++)
#pragma unroll
                        for (int kx = 0; kx < 3; kx++)
                            a = fmaf(wp[ky * 3 + kx], win[rr + ky][kx], a);
                    acc[j * 4 + rr] = a;
                }
            }
        }
        __syncthreads();
    }
#pragma unroll
    for (int j = 0; j < COPB; j++) {
        const float bb = bias[co0 + j];
#pragma unroll
        for (int rr = 0; rr < 4; rr++) {
            float v = acc[j * 4 + rr] + bb;
            if (TANH) v = tanhf(v);
            out[(long)b * obs + (long)(co0 + j) * PX + (long)f * ofs
                + (long)(tileY + r0 + rr) * 128 + tileX + tx] = v;
        }
    }
}

// ---------------- fused conv3x3 + ConvLSTM gates (strip version) -----------
template<int HCPB>
__global__ __launch_bounds__(256)
void conv_lstm_k(const float* __restrict__ in0, int c0, long bs0, long cst0,
                 const float* __restrict__ in1, int c1, long bs1, long cst1,
                 const float* __restrict__ sc, long sbs, long scst,
                 const float* __restrict__ w, const float* __restrict__ bias, int hidden,
                 const float* __restrict__ cprev, long cpbs,
                 float* __restrict__ hout, long hobs,
                 float* __restrict__ cout_, long cobs,
                 float* __restrict__ hout2, long ho2bs)
{
    __shared__ float lds[CI][1156];
    const int tid = threadIdx.x;
    const int tx = tid & 31, r0 = (tid >> 5) << 2;
    const int tileX = (blockIdx.x & 3) << 5, tileY = (blockIdx.x >> 2) << 5;
    const int b = blockIdx.z;
    const int cin = c0 + c1;
    const int hc0 = blockIdx.y * HCPB;
    float acc[HCPB * 16];                      // [hc][gate][rr]
#pragma unroll
    for (int j = 0; j < HCPB * 16; j++) acc[j] = 0.f;

    for (int cb = 0; cb < cin; cb += CI) {
        const int cmax = min(CI, cin - cb);
        for (int cl = 0; cl < cmax; cl++) {
            const int ci = cb + cl;
            const float* p; const float* sp = nullptr;
            if (ci < c0) {
                p = in0 + (long)b * bs0 + (long)ci * cst0;
                if (sc) sp = sc + (long)b * sbs + (long)ci * scst;
            } else {
                p = in1 + (long)b * bs1 + (long)(ci - c0) * cst1;
            }
            for (int idx = tid; idx < 1156; idx += 256) {
                const int r = idx / 34, cc = idx - r * 34;
                const int gy = tileY + r - 1, gx = tileX + cc - 1;
                float v = 0.f;
                if ((unsigned)gy < 128u && (unsigned)gx < 128u) {
                    const int pix = gy * 128 + gx;
                    v = p[pix];
                    if (sp) v *= sp[pix];
                }
                lds[cl][idx] = v;
            }
        }
        __syncthreads();
        for (int cl = 0; cl < cmax; cl++) {
            float win[6][3];
#pragma unroll
            for (int dy = 0; dy < 6; dy++)
#pragma unroll
                for (int dx = 0; dx < 3; dx++)
                    win[dy][dx] = lds[cl][(r0 + dy) * 34 + tx + dx];
            const int ci = cb + cl;
#pragma unroll
            for (int j = 0; j < HCPB; j++)
#pragma unroll
                for (int g = 0; g < 4; g++) {
                    const float* wp = w + ((long)(g * hidden + hc0 + j) * cin + ci) * 9;
#pragma unroll
                    for (int rr = 0; rr < 4; rr++) {
                        float a = acc[(j * 4 + g) * 4 + rr];
#pragma unroll
                        for (int ky = 0; ky < 3; ky++)
#pragma unroll
                            for (int kx = 0; kx < 3; kx++)
                                a = fmaf(wp[ky * 3 + kx], win[rr + ky][kx], a);
                        acc[(j * 4 + g) * 4 + rr] = a;
                    }
                }
        }
        __syncthreads();
    }
#pragma unroll
    for (int j = 0; j < HCPB; j++) {
        const int hc = hc0 + j;
        const float bi = bias[hc], bf = bias[hidden + hc];
        const float bo = bias[2 * hidden + hc], bg = bias[3 * hidden + hc];
#pragma unroll
        for (int rr = 0; rr < 4; rr++) {
            const long opix = (long)(tileY + r0 + rr) * 128 + tileX + tx;
            const float i_ = sigmoidf_(acc[(j * 4 + 0) * 4 + rr] + bi);
            const float f_ = sigmoidf_(acc[(j * 4 + 1) * 4 + rr] + bf);
            const float o_ = sigmoidf_(acc[(j * 4 + 2) * 4 + rr] + bo);
            const float g_ = tanhf(acc[(j * 4 + 3) * 4 + rr] + bg);
            const float cp = cprev[(long)b * cpbs + (long)hc * PX + opix];
            const float c2 = f_ * cp + i_ * g_;
            const float h2 = o_ * tanhf(c2);
            hout[(long)b * hobs + (long)hc * PX + opix] = h2;
            cout_[(long)b * cobs + (long)hc * PX + opix] = c2;
            if (hout2) hout2[(long)b * ho2bs + (long)hc * PX + opix] = h2;
        }
    }
}

// ---------------- fused decoder attention score ----------------------------
// score[b,t] = conv2( tanh( Zpart[t] + conv_y(y) ) ), 16x16 tile per block.
__global__ __launch_bounds__(256)
void attn_fuse_k(const float* __restrict__ y, long ybs,
                 const float* __restrict__ zpart,      // [slot][b][32][PX]
                 const float* __restrict__ wt1,        // (32,129,3,3); y-ch = 0
                 const float* __restrict__ wt2, const float* __restrict__ bt2,
                 float* __restrict__ score, int nb)
{
    __shared__ float ylds[400];                 // 20x20 y halo
    __shared__ float zl[32][324];               // z on 18x18
    const int tid = threadIdx.x;
    const int tileX = (blockIdx.x & 7) << 4, tileY = (blockIdx.x >> 3) << 4;
    const int z = blockIdx.z;
    const int b = z % nb, t = z / nb;

    for (int idx = tid; idx < 400; idx += 256) {
        const int r = idx / 20, c = idx - r * 20;
        const int gy = tileY + r - 2, gx = tileX + c - 2;
        ylds[idx] = ((unsigned)gy < 128u && (unsigned)gx < 128u)
                        ? y[(long)b * ybs + gy * 128 + gx] : 0.f;
    }
    __syncthreads();
    const float* zp0 = zpart + ((long)t * nb + b) * 32 * PX;
    for (int idx = tid; idx < 324; idx += 256) {
        const int zr = idx / 18, zc = idx - zr * 18;
        const int gy = tileY + zr - 1, gx = tileX + zc - 1;
        if ((unsigned)gy < 128u && (unsigned)gx < 128u) {
            float yw[9];
#pragma unroll
            for (int dy = 0; dy < 3; dy++)
#pragma unroll
                for (int dx = 0; dx < 3; dx++)
                    yw[dy * 3 + dx] = ylds[(zr + dy) * 20 + zc + dx];
            const long pix = (long)gy * 128 + gx;
#pragma unroll 8
            for (int ch = 0; ch < 32; ch++) {
                const float* wy = wt1 + (long)ch * 129 * 9;
                float s = zp0[(long)ch * PX + pix];
#pragma unroll
                for (int q = 0; q < 9; q++) s = fmaf(wy[q], yw[q], s);
                zl[ch][idx] = tanhf(s);
            }
        } else {
#pragma unroll 8
            for (int ch = 0; ch < 32; ch++) zl[ch][idx] = 0.f;
        }
    }
    __syncthreads();
    const int tx = tid & 15, ty = tid >> 4;
    float a = bt2[0];
    for (int ch = 0; ch < 32; ch++) {
#pragma unroll
        for (int ky = 0; ky < 3; ky++)
#pragma unroll
            for (int kx = 0; kx < 3; kx++)
                a = fmaf(wt2[ch * 9 + ky * 3 + kx], zl[ch][(ty + ky) * 18 + tx + kx], a);
    }
    score[((long)b * 10 + t) * PX + (long)(tileY + ty) * 128 + tileX + tx] = a;
}

// ---------------- softmax over 10 + multiply into A ------------------------
__global__ __launch_bounds__(256)
void softmax_mul_k(const float* __restrict__ s, float* __restrict__ A, int nb)
{
    const long idx = (long)blockIdx.x * 256 + threadIdx.x;
    if (idx >= (long)nb * PX) return;
    const long b = idx >> 14, p = idx & 16383;
    const float* base = s + b * 10 * PX + p;
    float v[10]; float m = -1e30f;
#pragma unroll
    for (int t = 0; t < 10; t++) { v[t] = base[t * PX]; m = fmaxf(m, v[t]); }
    float sum = 0.f;
#pragma unroll
    for (int t = 0; t < 10; t++) { v[t] = expf(v[t] - m); sum += v[t]; }
    const float r = 1.f / sum;
    float* Ab = A + b * 10 * PX + p;
#pragma unroll
    for (int t = 0; t < 10; t++) Ab[t * PX] *= v[t] * r;
}

// ---------------- softmax over 10 slots, in place --------------------------
__global__ __launch_bounds__(256)
void softmax_k(float* __restrict__ s, int nb)
{
    const long idx = (long)blockIdx.x * 256 + threadIdx.x;
    if (idx >= (long)nb * PX) return;
    const long b = idx >> 14, p = idx & 16383;
    float* base = s + b * 10 * PX + p;
    float v[10]; float m = -1e30f;
#pragma unroll
    for (int t = 0; t < 10; t++) { v[t] = base[t * PX]; m = fmaxf(m, v[t]); }
    float sum = 0.f;
#pragma unroll
    for (int t = 0; t < 10; t++) { v[t] = expf(v[t] - m); sum += v[t]; }
    const float r = 1.f / sum;
#pragma unroll
    for (int t = 0; t < 10; t++) base[t * PX] = v[t] * r;
}

__global__ __launch_bounds__(256)
void ones_k(float* __restrict__ A, long n)
{
    const long idx = (long)blockIdx.x * 256 + threadIdx.x;
    if (idx < n) A[idx] = 1.f;
}

// ------ temporal weighted sum: out[b,ch,p] = sum_t beta[b,t,p]*hb[t,b,ch,p] -
__global__ __launch_bounds__(256)
void wsum_k(const float* __restrict__ beta, const float* __restrict__ hb,
            float* __restrict__ out, int nb, long slot1)
{
    const long idx = (long)blockIdx.x * 256 + threadIdx.x;
    if (idx >= (long)nb * 64 * PX) return;
    const long p = idx & 16383;
    const long b = idx >> 20;          // idx / (64*PX)
    float a = 0.f;
#pragma unroll
    for (int t = 0; t < 10; t++)
        a += beta[(b * 10 + t) * PX + p] * hb[t * slot1 + idx];
    out[idx] = a;
}

// ---------------------------------------------------------------------------
extern "C" void kernel_launch(void* const* d_in, const int* in_sizes, int n_in,
                              void* d_out, int out_size, void* d_ws, size_t ws_size,
                              hipStream_t stream)
{
    const float* x      = (const float*)d_in[0];
    const float* h0     = (const float*)d_in[1];
    const float* c0     = (const float*)d_in[2];
    const float* h1     = (const float*)d_in[3];
    const float* c1     = (const float*)d_in[4];
    const float* w_enc0 = (const float*)d_in[5];
    const float* b_enc0 = (const float*)d_in[6];
    const float* w_enc1 = (const float*)d_in[7];
    const float* b_enc1 = (const float*)d_in[8];
    const float* w_dec0 = (const float*)d_in[9];
    const float* b_dec0 = (const float*)d_in[10];
    const float* w_dec1 = (const float*)d_in[11];
    const float* b_dec1 = (const float*)d_in[12];
    const float* wa1 = (const float*)d_in[13];
    const float* ba1 = (const float*)d_in[14];
    const float* wa2 = (const float*)d_in[15];
    const float* ba2 = (const float*)d_in[16];
    const float* wt1 = (const float*)d_in[17];
    const float* bt1 = (const float*)d_in[18];
    const float* wt2 = (const float*)d_in[19];
    const float* bt2 = (const float*)d_in[20];
    float* out = (float*)d_out;

    // ---- choose batch tile nb: need = 1704 * PX * nb floats ----
    int nb = 0;
    for (int cand = 8; cand >= 1; cand >>= 1) {
        const size_t need = (size_t)1704 * PX * cand * sizeof(float);
        if (need <= ws_size) { nb = cand; break; }
    }
    if (nb == 0) return;

    // ---- workspace layout (floats), per batch-group of nb ----
    float* ws = (float*)d_ws;
    const long slot0 = (long)nb * PX;
    const long slot1 = (long)nb * 64 * PX;
    float* hs0   = ws;                            // 10 * slot0
    float* cs0   = hs0 + 10 * slot0;              // 10 * slot0
    float* hs1   = cs0 + 10 * slot0;              // 10 * slot1
    float* cs1   = hs1 + 10 * slot1;              // 10 * slot1
    float* A     = cs1 + 10 * slot1;              // nb * 10 * PX
    float* score = A + (long)nb * 10 * PX;        // nb * 10 * PX
    float* zpart = score + (long)nb * 10 * PX;    // 10 * nb * 32 * PX
    float* z1    = zpart;                         // alias: z1 dead after encoder
    float* aht   = zpart + (long)10 * nb * 32 * PX;  // nb * 64 * PX

    const dim3 blk(256);
    const long TDP = (long)T_ * D_ * PX;
    const long zslot = (long)nb * 32 * PX;        // Zpart per-slot stride

    for (int b0 = 0; b0 < 8; b0 += nb) {
        const float* xb  = x  + (long)b0 * TDP;
        const float* h0b = h0 + (long)b0 * PX;
        const float* c0b = c0 + (long)b0 * PX;
        const float* h1b = h1 + (long)b0 * 64 * PX;
        const float* c1b = c1 + (long)b0 * 64 * PX;
        float* outb = out + (long)b0 * 5 * PX;

        ones_k<<<(int)((long)nb * 10 * PX / 256), blk, 0, stream>>>(A, (long)nb * 10 * PX);

        // ============ encoder layer 0 (compounding input attention) ============
        for (int t = 0; t < 10; t++) {
            const float* hprev = (t == 0) ? h0b : hs0 + (long)(t - 1) * slot0;
            const float* cprev = (t == 0) ? c0b : cs0 + (long)(t - 1) * slot0;
            conv3x3_k<8, true><<<dim3(16, 4, 10 * nb), blk, 0, stream>>>(
                xb, 10, TDP, (long)D_ * PX, PX,       // ch = t-axis, f = k
                hprev, 1, PX, PX, 0,
                cprev, 1, PX, PX, 0,
                A, 10 * PX, 0, PX,
                wa1, 12, ba1, z1, 32 * PX, zslot, nb);
            conv3x3_k<1, false><<<dim3(16, 1, 10 * nb), blk, 0, stream>>>(
                z1, 32, 32 * PX, PX, zslot,
                nullptr, 0, 0, 0, 0, nullptr, 0, 0, 0, 0,
                nullptr, 0, 0, 0,
                wa2, 32, ba2, score, 10 * PX, PX, nb);
            softmax_mul_k<<<nb * 64, blk, 0, stream>>>(score, A, nb);
            conv_lstm_k<1><<<dim3(16, 1, nb), blk, 0, stream>>>(
                xb + (long)t * D_ * PX, 10, TDP, PX,
                hprev, 1, PX, PX,
                A, 10 * PX, PX,
                w_enc0, b_enc0, 1,
                cprev, PX,
                hs0 + (long)t * slot0, PX,
                cs0 + (long)t * slot0, PX,
                (float*)nullptr, 0);
        }

        // ============ encoder layer 1 ============
        for (int t = 0; t < 10; t++) {
            const float* hprev = (t == 0) ? h1b : hs1 + (long)(t - 1) * slot1;
            const float* cprev = (t == 0) ? c1b : cs1 + (long)(t - 1) * slot1;
            conv_lstm_k<2><<<dim3(16, 32, nb), blk, 0, stream>>>(
                hs0 + (long)t * slot0, 1, PX, PX,
                hprev, 64, 64 * PX, PX,
                nullptr, 0, 0,
                w_enc1, b_enc1, 64,
                cprev, 64 * PX,
                hs1 + (long)t * slot1, 64 * PX,
                cs1 + (long)t * slot1, 64 * PX,
                (float*)nullptr, 0);
        }

        // ============ Zpart for all 10 encoder slots ============
        // Zpart[slot] = conv(wt1[:,1:129], [h_slot; c_slot]) + bt1
        conv3x3_k<8, false><<<dim3(16, 4, 10 * nb), blk, 0, stream>>>(
            hs1, 64, 64 * PX, PX, slot1,
            cs1, 64, 64 * PX, PX, slot1,
            nullptr, 0, 0, 0, 0,
            nullptr, 0, 0, 0,
            wt1 + 9, 129, bt1, zpart, 32 * PX, zslot, nb);

        // ============ decoder (5 steps) ============
        for (int s = 0; s < 5; s++) {
            const float* yptr; long ybs;
            if (s == 0) { yptr = xb + 9L * D_ * PX; ybs = TDP; }
            else        { yptr = hs0 + (long)(s - 1) * slot0; ybs = PX; }

            attn_fuse_k<<<dim3(64, 1, 10 * nb), blk, 0, stream>>>(
                yptr, ybs, zpart, wt1, wt2, bt2, score, nb);
            softmax_k<<<nb * 64, blk, 0, stream>>>(score, nb);
            wsum_k<<<(int)((long)nb * 64 * PX / 256), blk, 0, stream>>>(
                score, hs1, aht, nb, slot1);

            const int sl_new = s % 10;
            const int sl_last = (s + 9) % 10;
            conv_lstm_k<2><<<dim3(16, 32, nb), blk, 0, stream>>>(
                yptr, 1, ybs, PX,
                aht, 64, 64 * PX, PX,
                nullptr, 0, 0,
                w_dec0, b_dec0, 64,
                cs1 + (long)sl_last * slot1, 64 * PX,
                hs1 + (long)sl_new * slot1, 64 * PX,
                cs1 + (long)sl_new * slot1, 64 * PX,
                (float*)nullptr, 0);
            if (s < 4) {
                conv3x3_k<8, false><<<dim3(16, 4, nb), blk, 0, stream>>>(
                    hs1 + (long)sl_new * slot1, 64, 64 * PX, PX, 0,
                    cs1 + (long)sl_new * slot1, 64, 64 * PX, PX, 0,
                    nullptr, 0, 0, 0, 0,
                    nullptr, 0, 0, 0,
                    wt1 + 9, 129, bt1, zpart + (long)sl_new * zslot, 32 * PX, 0, nb);
            }
            conv_lstm_k<1><<<dim3(16, 1, nb), blk, 0, stream>>>(
                hs1 + (long)sl_new * slot1, 64, 64 * PX, PX,
                hs0 + (long)sl_last * slot0, 1, PX, PX,
                nullptr, 0, 0,
                w_dec1, b_dec1, 1,
                cs0 + (long)sl_last * slot0, PX,
                hs0 + (long)sl_new * slot0, PX,
                cs0 + (long)sl_new * slot0, PX,
                outb + (long)s * PX, 5 * PX);
        }
    }
}

// Round 4
// 26370.282 us; speedup vs baseline: 1.5675x; 1.1393x over previous
//
#include <hip/hip_runtime.h>

// ---------------------------------------------------------------------------
// WeatherModel ConvLSTM enc-dec, fp32, MI355X. Round 4: latency/occupancy
// attack. Evidence: round-3 speedup == FLOP ratio exactly => kernels are
// latency-bound at nb=1 (ws ~128MB). Changes: (1) encoder L0 fully batched
// (fused attention kernel, all-batch hs0/cs0/A = 21 MB); (2) per-group
// footprint 111.7 -> 86.2 MB/unit (cs1 2-slot, incremental zpart, 5-slot
// private decoder ring); (3) split-K + combine for small convs (zpart-update,
// dec LSTM1, enc-L0 LSTM); (4) fused softmax+wsum; (5) HCPB=1 at nb=1.
// ---------------------------------------------------------------------------

#define PX 16384L   // 128*128
#define T_ 10
#define D_ 10

__device__ __forceinline__ float sigmoidf_(float x) { return 1.f / (1.f + expf(-x)); }

// ============ fused conv3x3 + ConvLSTM gates, 32x32 tile, 4px strips =======
// hidden=64 layers. No input scaling. grid: (16, 64/HCPB, nb)
template<int HCPB>
__global__ __launch_bounds__(256)
void conv_lstm_k(const float* __restrict__ in0, int c0, long bs0, long cst0,
                 const float* __restrict__ in1, int c1, long bs1, long cst1,
                 const float* __restrict__ w, const float* __restrict__ bias, int hidden,
                 const float* __restrict__ cprev, long cpbs,
                 float* __restrict__ hout, long hobs,
                 float* __restrict__ cout_, long cobs)
{
    __shared__ float lds[4][1156];             // 34x34 halo per channel
    const int tid = threadIdx.x;
    const int tx = tid & 31, r0 = (tid >> 5) << 2;
    const int tileX = (blockIdx.x & 3) << 5, tileY = (blockIdx.x >> 2) << 5;
    const int b = blockIdx.z;
    const int cin = c0 + c1;
    const int hc0 = blockIdx.y * HCPB;
    float acc[HCPB * 16];                      // [hc][gate][rr]
#pragma unroll
    for (int j = 0; j < HCPB * 16; j++) acc[j] = 0.f;

    for (int cb = 0; cb < cin; cb += 4) {
        const int cmax = min(4, cin - cb);
        for (int cl = 0; cl < cmax; cl++) {
            const int ci = cb + cl;
            const float* p = (ci < c0) ? in0 + (long)b * bs0 + (long)ci * cst0
                                       : in1 + (long)b * bs1 + (long)(ci - c0) * cst1;
            for (int idx = tid; idx < 1156; idx += 256) {
                const int r = idx / 34, cc = idx - r * 34;
                const int gy = tileY + r - 1, gx = tileX + cc - 1;
                lds[cl][idx] = ((unsigned)gy < 128u && (unsigned)gx < 128u)
                                   ? p[gy * 128 + gx] : 0.f;
            }
        }
        __syncthreads();
        for (int cl = 0; cl < cmax; cl++) {
            float win[6][3];
#pragma unroll
            for (int dy = 0; dy < 6; dy++)
#pragma unroll
                for (int dx = 0; dx < 3; dx++)
                    win[dy][dx] = lds[cl][(r0 + dy) * 34 + tx + dx];
            const int ci = cb + cl;
#pragma unroll
            for (int j = 0; j < HCPB; j++)
#pragma unroll
                for (int g = 0; g < 4; g++) {
                    const float* wp = w + ((long)(g * hidden + hc0 + j) * cin + ci) * 9;
#pragma unroll
                    for (int rr = 0; rr < 4; rr++) {
                        float a = acc[(j * 4 + g) * 4 + rr];
#pragma unroll
                        for (int ky = 0; ky < 3; ky++)
#pragma unroll
                            for (int kx = 0; kx < 3; kx++)
                                a = fmaf(wp[ky * 3 + kx], win[rr + ky][kx], a);
                        acc[(j * 4 + g) * 4 + rr] = a;
                    }
                }
        }
        __syncthreads();
    }
#pragma unroll
    for (int j = 0; j < HCPB; j++) {
        const int hc = hc0 + j;
        const float bi = bias[hc], bf = bias[hidden + hc];
        const float bo = bias[2 * hidden + hc], bg = bias[3 * hidden + hc];
#pragma unroll
        for (int rr = 0; rr < 4; rr++) {
            const long opix = (long)(tileY + r0 + rr) * 128 + tileX + tx;
            const float i_ = sigmoidf_(acc[(j * 4 + 0) * 4 + rr] + bi);
            const float f_ = sigmoidf_(acc[(j * 4 + 1) * 4 + rr] + bf);
            const float o_ = sigmoidf_(acc[(j * 4 + 2) * 4 + rr] + bo);
            const float g_ = tanhf(acc[(j * 4 + 3) * 4 + rr] + bg);
            const float cp = cprev[(long)b * cpbs + (long)hc * PX + opix];
            const float c2 = f_ * cp + i_ * g_;
            const float h2 = o_ * tanhf(c2);
            hout[(long)b * hobs + (long)hc * PX + opix] = h2;
            cout_[(long)b * cobs + (long)hc * PX + opix] = c2;
        }
    }
}

// ============ split-K partial conv, 16x16 tile ==============================
// grid: (64, nco/COPB, nslices*nb); writes pbuf[((slice*nb+b)*nco+co)*PX+px]
template<int COPB>
__global__ __launch_bounds__(256)
void convp_k(const float* __restrict__ in0, int c0, long bs0, long cst0,
             const float* __restrict__ in1, long bs1, long cst1,
             const float* __restrict__ sc, long sbs, long scst,
             const float* __restrict__ w, int wcin, int wcoff,
             int4 cis, int4 cic,
             float* __restrict__ pbuf, int nco, int nb)
{
    __shared__ float lds[4][324];
    const int tid = threadIdx.x;
    const int tx = tid & 15, ty = tid >> 4;
    const int tileX = (blockIdx.x & 7) << 4, tileY = (blockIdx.x >> 3) << 4;
    const int z = blockIdx.z;
    const int b = z % nb, s = z / nb;
    const int ci0 = (s == 0) ? cis.x : (s == 1) ? cis.y : (s == 2) ? cis.z : cis.w;
    const int cn  = (s == 0) ? cic.x : (s == 1) ? cic.y : (s == 2) ? cic.z : cic.w;
    const int co0 = blockIdx.y * COPB;
    float acc[COPB];
#pragma unroll
    for (int j = 0; j < COPB; j++) acc[j] = 0.f;

    for (int cb = 0; cb < cn; cb += 4) {
        const int cmax = min(4, cn - cb);
        for (int cl = 0; cl < cmax; cl++) {
            const int ci = ci0 + cb + cl;
            const float* p; const float* sp = nullptr;
            if (ci < c0) {
                p = in0 + (long)b * bs0 + (long)ci * cst0;
                if (sc) sp = sc + (long)b * sbs + (long)ci * scst;
            } else {
                p = in1 + (long)b * bs1 + (long)(ci - c0) * cst1;
            }
            for (int idx = tid; idx < 324; idx += 256) {
                const int r = idx / 18, cc = idx - r * 18;
                const int gy = tileY + r - 1, gx = tileX + cc - 1;
                float v = 0.f;
                if ((unsigned)gy < 128u && (unsigned)gx < 128u) {
                    v = p[gy * 128 + gx];
                    if (sp) v *= sp[gy * 128 + gx];
                }
                lds[cl][idx] = v;
            }
        }
        __syncthreads();
        for (int cl = 0; cl < cmax; cl++) {
            float r9[9];
#pragma unroll
            for (int dy = 0; dy < 3; dy++)
#pragma unroll
                for (int dx = 0; dx < 3; dx++)
                    r9[dy * 3 + dx] = lds[cl][(ty + dy) * 18 + tx + dx];
            const int ci = ci0 + cb + cl;
#pragma unroll
            for (int j = 0; j < COPB; j++) {
                const float* wp = w + ((long)(co0 + j) * wcin + wcoff + ci) * 9;
                float a = acc[j];
#pragma unroll
                for (int q = 0; q < 9; q++) a = fmaf(wp[q], r9[q], a);
                acc[j] = a;
            }
        }
        __syncthreads();
    }
    const long opix = (long)(tileY + ty) * 128 + tileX + tx;
#pragma unroll
    for (int j = 0; j < COPB; j++)
        pbuf[(((long)s * nb + b) * nco + co0 + j) * PX + opix] = acc[j];
}

// ============ combine split-K partials + bias -> out [b][nco][PX] ==========
__global__ __launch_bounds__(256)
void combine_add_k(const float* __restrict__ pbuf, int nsl, int nco,
                   const float* __restrict__ bias, float* __restrict__ out, int nb)
{
    const long idx = (long)blockIdx.x * 256 + threadIdx.x;
    if (idx >= (long)nb * nco * PX) return;
    const long px = idx & 16383;
    const long v = idx >> 14;
    const int co = (int)(v % nco), b = (int)(v / nco);
    float a = bias[co];
    for (int s = 0; s < nsl; s++)
        a += pbuf[(((long)s * nb + b) * nco + co) * PX + px];
    out[((long)b * nco + co) * PX + px] = a;
}

// ============ combine split-K LSTM gate partials -> h,c,out2 ===============
__global__ __launch_bounds__(256)
void combine_lstm_k(const float* __restrict__ pbuf, int nsl, int hidden,
                    const float* __restrict__ bias,
                    const float* __restrict__ cprev, long cpbs,
                    float* __restrict__ hout, long hobs,
                    float* __restrict__ cout_, long cobs,
                    float* __restrict__ hout2, long ho2bs, int nb)
{
    const long idx = (long)blockIdx.x * 256 + threadIdx.x;
    if (idx >= (long)nb * hidden * PX) return;
    const long px = idx & 16383;
    const long v = idx >> 14;
    const int hc = (int)(v % hidden), b = (int)(v / hidden);
    const int nco = 4 * hidden;
    float g4[4] = {0.f, 0.f, 0.f, 0.f};
    for (int s = 0; s < nsl; s++)
#pragma unroll
        for (int g = 0; g < 4; g++)
            g4[g] += pbuf[(((long)s * nb + b) * nco + g * hidden + hc) * PX + px];
    const float i_ = sigmoidf_(g4[0] + bias[hc]);
    const float f_ = sigmoidf_(g4[1] + bias[hidden + hc]);
    const float o_ = sigmoidf_(g4[2] + bias[2 * hidden + hc]);
    const float g_ = tanhf(g4[3] + bias[3 * hidden + hc]);
    const float cp = cprev[(long)b * cpbs + (long)hc * PX + px];
    const float c2 = f_ * cp + i_ * g_;
    const float h2 = o_ * tanhf(c2);
    hout[(long)b * hobs + (long)hc * PX + px] = h2;
    cout_[(long)b * cobs + (long)hc * PX + px] = c2;
    if (hout2) hout2[(long)b * ho2bs + (long)hc * PX + px] = h2;
}

// ============ fused input-attention score (phase 1, full batch) ============
// score[b,k] = conv2( tanh( conv1([x[b,:,k]*A[b,k], h, c]) ) )
// grid: (64, 1, k*8+b), block 256. LDS: xl 19.2KB + zl 41.5KB.
__global__ __launch_bounds__(256)
void iattn_k(const float* __restrict__ x, const float* __restrict__ A,
             const float* __restrict__ h, const float* __restrict__ c,
             const float* __restrict__ wa1, const float* __restrict__ ba1,
             const float* __restrict__ wa2, const float* __restrict__ ba2,
             float* __restrict__ score)
{
    __shared__ float xl[12][400];              // 12 ch on 20x20 halo
    __shared__ float zl[32][324];              // conv1 out on 18x18
    const int tid = threadIdx.x;
    const int tileX = (blockIdx.x & 7) << 4, tileY = (blockIdx.x >> 3) << 4;
    const int z = blockIdx.z;
    const int b = z & 7, k = z >> 3;

    float* aT = &zl[0][0];                     // 400-float temp (overwritten later)
    for (int idx = tid; idx < 400; idx += 256) {
        const int r = idx / 20, cc = idx - r * 20;
        const int gy = tileY + r - 2, gx = tileX + cc - 2;
        aT[idx] = ((unsigned)gy < 128u && (unsigned)gx < 128u)
                      ? A[((long)b * 10 + k) * PX + gy * 128 + gx] : 0.f;
    }
    __syncthreads();
    for (int ch = 0; ch < 12; ch++) {
        const float* p = (ch < 10) ? x + (((long)b * 10 + ch) * 10 + k) * PX
                       : (ch == 10) ? h + (long)b * PX : c + (long)b * PX;
        for (int idx = tid; idx < 400; idx += 256) {
            const int r = idx / 20, cc = idx - r * 20;
            const int gy = tileY + r - 2, gx = tileX + cc - 2;
            float v = 0.f;
            if ((unsigned)gy < 128u && (unsigned)gx < 128u) {
                v = p[gy * 128 + gx];
                if (ch < 10) v *= aT[idx];
            }
            xl[ch][idx] = v;
        }
    }
    __syncthreads();
    // conv1: each thread handles idx tid and tid+256 over the 18x18 grid
    const int i0 = tid, i1 = tid + 256;
    const int zr0 = i0 / 18, zc0 = i0 - zr0 * 18;
    const int zr1 = (i1 < 324) ? i1 / 18 : 0, zc1 = (i1 < 324) ? i1 - (i1 / 18) * 18 : 0;
    float acc0[32], acc1[32];
#pragma unroll
    for (int co = 0; co < 32; co++) { acc0[co] = 0.f; acc1[co] = 0.f; }
    for (int ci = 0; ci < 12; ci++) {
        float wA[9], wB[9];
#pragma unroll
        for (int dy = 0; dy < 3; dy++)
#pragma unroll
            for (int dx = 0; dx < 3; dx++) {
                wA[dy * 3 + dx] = xl[ci][(zr0 + dy) * 20 + zc0 + dx];
                wB[dy * 3 + dx] = xl[ci][(zr1 + dy) * 20 + zc1 + dx];
            }
#pragma unroll
        for (int co = 0; co < 32; co++) {
            const float* wp = wa1 + ((long)co * 12 + ci) * 9;
            float a0 = acc0[co], a1 = acc1[co];
#pragma unroll
            for (int q = 0; q < 9; q++) { a0 = fmaf(wp[q], wA[q], a0); a1 = fmaf(wp[q], wB[q], a1); }
            acc0[co] = a0; acc1[co] = a1;
        }
    }
    __syncthreads();   // all xl/aT reads done before zl overwrite
    {
        const int gy0 = tileY + zr0 - 1, gx0 = tileX + zc0 - 1;
        const bool in0_ = ((unsigned)gy0 < 128u && (unsigned)gx0 < 128u);
        const int gy1 = tileY + zr1 - 1, gx1 = tileX + zc1 - 1;
        const bool in1_ = (i1 < 324) && ((unsigned)gy1 < 128u && (unsigned)gx1 < 128u);
#pragma unroll
        for (int co = 0; co < 32; co++) {
            zl[co][i0] = in0_ ? tanhf(acc0[co] + ba1[co]) : 0.f;
            if (i1 < 324) zl[co][i1] = in1_ ? tanhf(acc1[co] + ba1[co]) : 0.f;
        }
    }
    __syncthreads();
    const int tx = tid & 15, ty = tid >> 4;
    float a = ba2[0];
    for (int co = 0; co < 32; co++) {
#pragma unroll
        for (int ky = 0; ky < 3; ky++)
#pragma unroll
            for (int kx = 0; kx < 3; kx++)
                a = fmaf(wa2[co * 9 + ky * 3 + kx], zl[co][(ty + ky) * 18 + tx + kx], a);
    }
    score[((long)b * 10 + k) * PX + (long)(tileY + ty) * 128 + tileX + tx] = a;
}

// ============ softmax over 10 (+optional compound into A) ==================
__global__ __launch_bounds__(256)
void softmax_mul_k(const float* __restrict__ s, float* __restrict__ A, int nb, int init)
{
    const long idx = (long)blockIdx.x * 256 + threadIdx.x;
    if (idx >= (long)nb * PX) return;
    const long b = idx >> 14, p = idx & 16383;
    const float* base = s + b * 10 * PX + p;
    float v[10]; float m = -1e30f;
#pragma unroll
    for (int t = 0; t < 10; t++) { v[t] = base[t * PX]; m = fmaxf(m, v[t]); }
    float sum = 0.f;
#pragma unroll
    for (int t = 0; t < 10; t++) { v[t] = expf(v[t] - m); sum += v[t]; }
    const float r = 1.f / sum;
    float* Ab = A + b * 10 * PX + p;
#pragma unroll
    for (int t = 0; t < 10; t++)
        Ab[t * PX] = init ? (v[t] * r) : (Ab[t * PX] * v[t] * r);
}

// ============ decoder attention score (y-part fused with cached Zpart) =====
__global__ __launch_bounds__(256)
void attn_fuse_k(const float* __restrict__ y, long ybs,
                 const float* __restrict__ zpart,      // [slot][b][32][PX]
                 const float* __restrict__ wt1,        // (32,129,3,3); y-ch = 0
                 const float* __restrict__ wt2, const float* __restrict__ bt2,
                 float* __restrict__ score, int nb)
{
    __shared__ float ylds[400];
    __shared__ float zl[32][324];
    const int tid = threadIdx.x;
    const int tileX = (blockIdx.x & 7) << 4, tileY = (blockIdx.x >> 3) << 4;
    const int z = blockIdx.z;
    const int b = z % nb, t = z / nb;

    for (int idx = tid; idx < 400; idx += 256) {
        const int r = idx / 20, c = idx - r * 20;
        const int gy = tileY + r - 2, gx = tileX + c - 2;
        ylds[idx] = ((unsigned)gy < 128u && (unsigned)gx < 128u)
                        ? y[(long)b * ybs + gy * 128 + gx] : 0.f;
    }
    __syncthreads();
    const float* zp0 = zpart + ((long)t * nb + b) * 32 * PX;
    for (int idx = tid; idx < 324; idx += 256) {
        const int zr = idx / 18, zc = idx - zr * 18;
        const int gy = tileY + zr - 1, gx = tileX + zc - 1;
        if ((unsigned)gy < 128u && (unsigned)gx < 128u) {
            float yw[9];
#pragma unroll
            for (int dy = 0; dy < 3; dy++)
#pragma unroll
                for (int dx = 0; dx < 3; dx++)
                    yw[dy * 3 + dx] = ylds[(zr + dy) * 20 + zc + dx];
            const long pix = (long)gy * 128 + gx;
#pragma unroll 8
            for (int ch = 0; ch < 32; ch++) {
                const float* wy = wt1 + (long)ch * 129 * 9;
                float s = zp0[(long)ch * PX + pix];
#pragma unroll
                for (int q = 0; q < 9; q++) s = fmaf(wy[q], yw[q], s);
                zl[ch][idx] = tanhf(s);
            }
        } else {
#pragma unroll 8
            for (int ch = 0; ch < 32; ch++) zl[ch][idx] = 0.f;
        }
    }
    __syncthreads();
    const int tx = tid & 15, ty = tid >> 4;
    float a = bt2[0];
    for (int ch = 0; ch < 32; ch++) {
#pragma unroll
        for (int ky = 0; ky < 3; ky++)
#pragma unroll
            for (int kx = 0; kx < 3; kx++)
                a = fmaf(wt2[ch * 9 + ky * 3 + kx], zl[ch][(ty + ky) * 18 + tx + kx], a);
    }
    score[((long)b * 10 + t) * PX + (long)(tileY + ty) * 128 + tileX + tx] = a;
}

// ============ fused softmax + temporal weighted sum ========================
__global__ __launch_bounds__(256)
void smax_wsum_k(const float* __restrict__ score, const float* __restrict__ hs1,
                 float* __restrict__ aht, int nb)
{
    const long idx = (long)blockIdx.x * 256 + threadIdx.x;
    if (idx >= (long)nb * PX) return;
    const long b = idx >> 14, p = idx & 16383;
    const float* base = score + b * 10 * PX + p;
    float v[10]; float m = -1e30f;
#pragma unroll
    for (int t = 0; t < 10; t++) { v[t] = base[t * PX]; m = fmaxf(m, v[t]); }
    float sum = 0.f;
#pragma unroll
    for (int t = 0; t < 10; t++) { v[t] = expf(v[t] - m); sum += v[t]; }
    const float r = 1.f / sum;
#pragma unroll
    for (int t = 0; t < 10; t++) v[t] *= r;
    const long slot1 = (long)nb * 64 * PX;
    for (int ch = 0; ch < 64; ch++) {
        float a = 0.f;
#pragma unroll
        for (int t = 0; t < 10; t++)
            a += v[t] * hs1[t * slot1 + (b * 64 + ch) * PX + p];
        aht[(b * 64 + ch) * PX + p] = a;
    }
}

// ---------------------------------------------------------------------------
extern "C" void kernel_launch(void* const* d_in, const int* in_sizes, int n_in,
                              void* d_out, int out_size, void* d_ws, size_t ws_size,
                              hipStream_t stream)
{
    const float* x      = (const float*)d_in[0];
    const float* h0     = (const float*)d_in[1];
    const float* c0in   = (const float*)d_in[2];
    const float* h1     = (const float*)d_in[3];
    const float* c1     = (const float*)d_in[4];
    const float* w_enc0 = (const float*)d_in[5];
    const float* b_enc0 = (const float*)d_in[6];
    const float* w_enc1 = (const float*)d_in[7];
    const float* b_enc1 = (const float*)d_in[8];
    const float* w_dec0 = (const float*)d_in[9];
    const float* b_dec0 = (const float*)d_in[10];
    const float* w_dec1 = (const float*)d_in[11];
    const float* b_dec1 = (const float*)d_in[12];
    const float* wa1 = (const float*)d_in[13];
    const float* ba1 = (const float*)d_in[14];
    const float* wa2 = (const float*)d_in[15];
    const float* ba2 = (const float*)d_in[16];
    const float* wt1 = (const float*)d_in[17];
    const float* bt1 = (const float*)d_in[18];
    const float* wt2 = (const float*)d_in[19];
    const float* bt2 = (const float*)d_in[20];
    float* out = (float*)d_out;

    // ---- adaptive batch tile for phase 2: need = (160 + 1316*nb)*PX*4 B ----
    int nb = 0;
    for (int cand = 8; cand >= 1; cand >>= 1) {
        const size_t need = (size_t)(160 + 1316 * cand) * PX * sizeof(float);
        if (need <= ws_size) { nb = cand; break; }
    }
    if (nb == 0) return;

    float* ws = (float*)d_ws;
    float* hs0 = ws;                      // [10][8][PX]
    float* cs0 = hs0 + 80 * PX;           // [10][8][PX]
    float* G   = cs0 + 80 * PX;
    // phase-1 aliases inside G
    float* A    = G;                      // [8][10][PX]
    float* sc1  = G + 80 * PX;            // [8][10][PX]
    float* pb0  = G + 160 * PX;           // [1][8][4][PX]
    // phase-2 per-group layout inside G
    const long slot1  = (long)nb * 64 * PX;          // hs1 per-t slot
    float* hs1   = G;                                 // 10 * slot1
    float* cs1   = hs1 + 10 * slot1;                  // 2 * slot1 (ping-pong)
    float* zpart = cs1 + 2 * slot1;                   // [10][nb][32][PX]
    float* aht   = zpart + (long)10 * nb * 32 * PX;   // [nb][64][PX]
    float* zpp   = aht + (long)nb * 64 * PX;          // [4][nb][32][PX]
    float* l1p   = zpp + (long)4 * nb * 32 * PX;      // [4][nb][4][PX]
    float* hs0g  = l1p + (long)4 * nb * 4 * PX;       // [5][nb][PX]
    float* cs0g  = hs0g + (long)5 * nb * PX;          // [5][nb][PX]
    float* scD   = cs0g + (long)5 * nb * PX;          // [nb][10][PX]

    const dim3 blk(256);
    const long TDP = (long)T_ * D_ * PX;
    const long zslot = (long)nb * 32 * PX;

    // ================= phase 1: encoder layer 0, FULL batch =================
    for (int t = 0; t < 10; t++) {
        const float* hprev = (t == 0) ? h0 : hs0 + (long)(t - 1) * 8 * PX;
        const float* cprev = (t == 0) ? c0in : cs0 + (long)(t - 1) * 8 * PX;
        iattn_k<<<dim3(64, 1, 80), blk, 0, stream>>>(
            x, A, hprev, cprev, wa1, ba1, wa2, ba2, sc1);
        softmax_mul_k<<<512, blk, 0, stream>>>(sc1, A, 8, t == 0);
        convp_k<4><<<dim3(64, 1, 8), blk, 0, stream>>>(
            x + (long)t * D_ * PX, 10, TDP, PX,
            hprev, PX, PX,
            A, 10 * PX, PX,
            w_enc0, 11, 0,
            make_int4(0, 0, 0, 0), make_int4(11, 0, 0, 0),
            pb0, 4, 8);
        combine_lstm_k<<<512, blk, 0, stream>>>(
            pb0, 1, 1, b_enc0, cprev, PX,
            hs0 + (long)t * 8 * PX, PX,
            cs0 + (long)t * 8 * PX, PX,
            (float*)nullptr, 0, 8);
    }

    // ================= phase 2: per batch-group =================
    const int HC = (nb >= 2) ? 2 : 1;     // HCPB for hidden-64 conv-LSTMs
    for (int b0 = 0; b0 < 8; b0 += nb) {
        const float* xb  = x + (long)b0 * TDP;
        const float* h1b = h1 + (long)b0 * 64 * PX;
        const float* c1b = c1 + (long)b0 * 64 * PX;
        float* outb = out + (long)b0 * 5 * PX;

        // -------- encoder layer 1 + incremental Zpart --------
        for (int t = 0; t < 10; t++) {
            const float* hprev = (t == 0) ? h1b : hs1 + (long)(t - 1) * slot1;
            const float* cprev = (t == 0) ? c1b : cs1 + (long)((t + 1) & 1) * slot1;
            if (HC == 2)
                conv_lstm_k<2><<<dim3(16, 32, nb), blk, 0, stream>>>(
                    hs0 + (long)t * 8 * PX + (long)b0 * PX, 1, PX, PX,
                    hprev, 64, 64 * PX, PX,
                    w_enc1, b_enc1, 64, cprev, 64 * PX,
                    hs1 + (long)t * slot1, 64 * PX,
                    cs1 + (long)(t & 1) * slot1, 64 * PX);
            else
                conv_lstm_k<1><<<dim3(16, 64, nb), blk, 0, stream>>>(
                    hs0 + (long)t * 8 * PX + (long)b0 * PX, 1, PX, PX,
                    hprev, 64, 64 * PX, PX,
                    w_enc1, b_enc1, 64, cprev, 64 * PX,
                    hs1 + (long)t * slot1, 64 * PX,
                    cs1 + (long)(t & 1) * slot1, 64 * PX);
            convp_k<8><<<dim3(64, 4, 4 * nb), blk, 0, stream>>>(
                hs1 + (long)t * slot1, 64, 64 * PX, PX,
                cs1 + (long)(t & 1) * slot1, 64 * PX, PX,
                nullptr, 0, 0,
                wt1, 129, 1,
                make_int4(0, 32, 64, 96), make_int4(32, 32, 32, 32),
                zpp, 32, nb);
            combine_add_k<<<(int)(((long)nb * 32 * PX + 255) / 256), blk, 0, stream>>>(
                zpp, 4, 32, bt1, zpart + (long)t * zslot, nb);
        }

        // -------- decoder (5 steps) --------
        for (int s = 0; s < 5; s++) {
            const float* yptr; long ybs;
            if (s == 0) { yptr = xb + 9L * D_ * PX; ybs = TDP; }
            else        { yptr = hs0g + (long)(s - 1) * nb * PX; ybs = PX; }
            const float* hb1 = (s == 0) ? hs0 + 9L * 8 * PX + (long)b0 * PX
                                        : hs0g + (long)(s - 1) * nb * PX;
            const float* cb1 = (s == 0) ? cs0 + 9L * 8 * PX + (long)b0 * PX
                                        : cs0g + (long)(s - 1) * nb * PX;

            attn_fuse_k<<<dim3(64, 1, 10 * nb), blk, 0, stream>>>(
                yptr, ybs, zpart, wt1, wt2, bt2, scD, nb);
            smax_wsum_k<<<(int)(((long)nb * PX + 255) / 256), blk, 0, stream>>>(
                scD, hs1, aht, nb);

            // decoder LSTM 0: in = [y(1); aht(64)], c = cs1[(s+1)&1]
            if (HC == 2)
                conv_lstm_k<2><<<dim3(16, 32, nb), blk, 0, stream>>>(
                    yptr, 1, ybs, PX, aht, 64, 64 * PX, PX,
                    w_dec0, b_dec0, 64,
                    cs1 + (long)((s + 1) & 1) * slot1, 64 * PX,
                    hs1 + (long)s * slot1, 64 * PX,
                    cs1 + (long)(s & 1) * slot1, 64 * PX);
            else
                conv_lstm_k<1><<<dim3(16, 64, nb), blk, 0, stream>>>(
                    yptr, 1, ybs, PX, aht, 64, 64 * PX, PX,
                    w_dec0, b_dec0, 64,
                    cs1 + (long)((s + 1) & 1) * slot1, 64 * PX,
                    hs1 + (long)s * slot1, 64 * PX,
                    cs1 + (long)(s & 1) * slot1, 64 * PX);

            // decoder LSTM 1 (split-K): in = [ht(64); hb1(1)]
            convp_k<4><<<dim3(64, 1, 4 * nb), blk, 0, stream>>>(
                hs1 + (long)s * slot1, 64, 64 * PX, PX,
                hb1, PX, PX,
                nullptr, 0, 0,
                w_dec1, 65, 0,
                make_int4(0, 17, 33, 49), make_int4(17, 16, 16, 16),
                l1p, 4, nb);
            combine_lstm_k<<<(int)(((long)nb * PX + 255) / 256), blk, 0, stream>>>(
                l1p, 4, 1, b_dec1, cb1, PX,
                hs0g + (long)s * nb * PX, PX,
                cs0g + (long)s * nb * PX, PX,
                outb + (long)s * PX, 5 * PX, nb);

            // Zpart update for rewritten slot s (skip last step)
            if (s < 4) {
                convp_k<8><<<dim3(64, 4, 4 * nb), blk, 0, stream>>>(
                    hs1 + (long)s * slot1, 64, 64 * PX, PX,
                    cs1 + (long)(s & 1) * slot1, 64 * PX, PX,
                    nullptr, 0, 0,
                    wt1, 129, 1,
                    make_int4(0, 32, 64, 96), make_int4(32, 32, 32, 32),
                    zpp, 32, nb);
                combine_add_k<<<(int)(((long)nb * 32 * PX + 255) / 256), blk, 0, stream>>>(
                    zpp, 4, 32, bt1, zpart + (long)s * zslot, nb);
            }
        }
    }
}

// Round 5
// 25973.004 us; speedup vs baseline: 1.5915x; 1.0153x over previous
//
#include <hip/hip_runtime.h>

// ---------------------------------------------------------------------------
// WeatherModel ConvLSTM enc-dec, fp32, MI355X. Round 5: memory-amplification
// fix. Evidence model: hidden-64 conv at HCPB=1 re-reads its 65-ch input once
// per output block (307 MB/call -> 49us HBM floor > 35us issue floor).
// Changes vs round 4: (1) conv_lstm HCPB=2 always (halves input re-reads);
// (2) CI=8 LDS staging (half the barriers); (3) smax_wsum split into 8
// channel-groups (512 blocks at nb=1 instead of 64). Layout/tiers unchanged.
// ---------------------------------------------------------------------------

#define PX 16384L   // 128*128
#define T_ 10
#define D_ 10

__device__ __forceinline__ float sigmoidf_(float x) { return 1.f / (1.f + expf(-x)); }

// ============ fused conv3x3 + ConvLSTM gates, 32x32 tile, 4px strips =======
// hidden=64 layers. grid: (16, 32, nb), HCPB=2, CI=8.
__global__ __launch_bounds__(256)
void conv_lstm_k(const float* __restrict__ in0, int c0, long bs0, long cst0,
                 const float* __restrict__ in1, int c1, long bs1, long cst1,
                 const float* __restrict__ w, const float* __restrict__ bias, int hidden,
                 const float* __restrict__ cprev, long cpbs,
                 float* __restrict__ hout, long hobs,
                 float* __restrict__ cout_, long cobs)
{
    __shared__ float lds[8][1156];             // 34x34 halo per channel, CI=8
    const int tid = threadIdx.x;
    const int tx = tid & 31, r0 = (tid >> 5) << 2;
    const int tileX = (blockIdx.x & 3) << 5, tileY = (blockIdx.x >> 2) << 5;
    const int b = blockIdx.z;
    const int cin = c0 + c1;
    const int hc0 = blockIdx.y * 2;
    float acc[32];                             // [hc(2)][gate(4)][rr(4)]
#pragma unroll
    for (int j = 0; j < 32; j++) acc[j] = 0.f;

    for (int cb = 0; cb < cin; cb += 8) {
        const int cmax = min(8, cin - cb);
        for (int cl = 0; cl < cmax; cl++) {
            const int ci = cb + cl;
            const float* p = (ci < c0) ? in0 + (long)b * bs0 + (long)ci * cst0
                                       : in1 + (long)b * bs1 + (long)(ci - c0) * cst1;
            for (int idx = tid; idx < 1156; idx += 256) {
                const int r = idx / 34, cc = idx - r * 34;
                const int gy = tileY + r - 1, gx = tileX + cc - 1;
                lds[cl][idx] = ((unsigned)gy < 128u && (unsigned)gx < 128u)
                                   ? p[gy * 128 + gx] : 0.f;
            }
        }
        __syncthreads();
        for (int cl = 0; cl < cmax; cl++) {
            float win[6][3];
#pragma unroll
            for (int dy = 0; dy < 6; dy++)
#pragma unroll
                for (int dx = 0; dx < 3; dx++)
                    win[dy][dx] = lds[cl][(r0 + dy) * 34 + tx + dx];
            const int ci = cb + cl;
#pragma unroll
            for (int j = 0; j < 2; j++)
#pragma unroll
                for (int g = 0; g < 4; g++) {
                    const float* wp = w + ((long)(g * hidden + hc0 + j) * cin + ci) * 9;
#pragma unroll
                    for (int rr = 0; rr < 4; rr++) {
                        float a = acc[(j * 4 + g) * 4 + rr];
#pragma unroll
                        for (int ky = 0; ky < 3; ky++)
#pragma unroll
                            for (int kx = 0; kx < 3; kx++)
                                a = fmaf(wp[ky * 3 + kx], win[rr + ky][kx], a);
                        acc[(j * 4 + g) * 4 + rr] = a;
                    }
                }
        }
        __syncthreads();
    }
#pragma unroll
    for (int j = 0; j < 2; j++) {
        const int hc = hc0 + j;
        const float bi = bias[hc], bf = bias[hidden + hc];
        const float bo = bias[2 * hidden + hc], bg = bias[3 * hidden + hc];
#pragma unroll
        for (int rr = 0; rr < 4; rr++) {
            const long opix = (long)(tileY + r0 + rr) * 128 + tileX + tx;
            const float i_ = sigmoidf_(acc[(j * 4 + 0) * 4 + rr] + bi);
            const float f_ = sigmoidf_(acc[(j * 4 + 1) * 4 + rr] + bf);
            const float o_ = sigmoidf_(acc[(j * 4 + 2) * 4 + rr] + bo);
            const float g_ = tanhf(acc[(j * 4 + 3) * 4 + rr] + bg);
            const float cp = cprev[(long)b * cpbs + (long)hc * PX + opix];
            const float c2 = f_ * cp + i_ * g_;
            const float h2 = o_ * tanhf(c2);
            hout[(long)b * hobs + (long)hc * PX + opix] = h2;
            cout_[(long)b * cobs + (long)hc * PX + opix] = c2;
        }
    }
}

// ============ split-K partial conv, 16x16 tile ==============================
// grid: (64, nco/COPB, nslices*nb); writes pbuf[((slice*nb+b)*nco+co)*PX+px]
template<int COPB>
__global__ __launch_bounds__(256)
void convp_k(const float* __restrict__ in0, int c0, long bs0, long cst0,
             const float* __restrict__ in1, long bs1, long cst1,
             const float* __restrict__ sc, long sbs, long scst,
             const float* __restrict__ w, int wcin, int wcoff,
             int4 cis, int4 cic,
             float* __restrict__ pbuf, int nco, int nb)
{
    __shared__ float lds[4][324];
    const int tid = threadIdx.x;
    const int tx = tid & 15, ty = tid >> 4;
    const int tileX = (blockIdx.x & 7) << 4, tileY = (blockIdx.x >> 3) << 4;
    const int z = blockIdx.z;
    const int b = z % nb, s = z / nb;
    const int ci0 = (s == 0) ? cis.x : (s == 1) ? cis.y : (s == 2) ? cis.z : cis.w;
    const int cn  = (s == 0) ? cic.x : (s == 1) ? cic.y : (s == 2) ? cic.z : cic.w;
    const int co0 = blockIdx.y * COPB;
    float acc[COPB];
#pragma unroll
    for (int j = 0; j < COPB; j++) acc[j] = 0.f;

    for (int cb = 0; cb < cn; cb += 4) {
        const int cmax = min(4, cn - cb);
        for (int cl = 0; cl < cmax; cl++) {
            const int ci = ci0 + cb + cl;
            const float* p; const float* sp = nullptr;
            if (ci < c0) {
                p = in0 + (long)b * bs0 + (long)ci * cst0;
                if (sc) sp = sc + (long)b * sbs + (long)ci * scst;
            } else {
                p = in1 + (long)b * bs1 + (long)(ci - c0) * cst1;
            }
            for (int idx = tid; idx < 324; idx += 256) {
                const int r = idx / 18, cc = idx - r * 18;
                const int gy = tileY + r - 1, gx = tileX + cc - 1;
                float v = 0.f;
                if ((unsigned)gy < 128u && (unsigned)gx < 128u) {
                    v = p[gy * 128 + gx];
                    if (sp) v *= sp[gy * 128 + gx];
                }
                lds[cl][idx] = v;
            }
        }
        __syncthreads();
        for (int cl = 0; cl < cmax; cl++) {
            float r9[9];
#pragma unroll
            for (int dy = 0; dy < 3; dy++)
#pragma unroll
                for (int dx = 0; dx < 3; dx++)
                    r9[dy * 3 + dx] = lds[cl][(ty + dy) * 18 + tx + dx];
            const int ci = ci0 + cb + cl;
#pragma unroll
            for (int j = 0; j < COPB; j++) {
                const float* wp = w + ((long)(co0 + j) * wcin + wcoff + ci) * 9;
                float a = acc[j];
#pragma unroll
                for (int q = 0; q < 9; q++) a = fmaf(wp[q], r9[q], a);
                acc[j] = a;
            }
        }
        __syncthreads();
    }
    const long opix = (long)(tileY + ty) * 128 + tileX + tx;
#pragma unroll
    for (int j = 0; j < COPB; j++)
        pbuf[(((long)s * nb + b) * nco + co0 + j) * PX + opix] = acc[j];
}

// ============ combine split-K partials + bias -> out [b][nco][PX] ==========
__global__ __launch_bounds__(256)
void combine_add_k(const float* __restrict__ pbuf, int nsl, int nco,
                   const float* __restrict__ bias, float* __restrict__ out, int nb)
{
    const long idx = (long)blockIdx.x * 256 + threadIdx.x;
    if (idx >= (long)nb * nco * PX) return;
    const long px = idx & 16383;
    const long v = idx >> 14;
    const int co = (int)(v % nco), b = (int)(v / nco);
    float a = bias[co];
    for (int s = 0; s < nsl; s++)
        a += pbuf[(((long)s * nb + b) * nco + co) * PX + px];
    out[((long)b * nco + co) * PX + px] = a;
}

// ============ combine split-K LSTM gate partials -> h,c,out2 ===============
__global__ __launch_bounds__(256)
void combine_lstm_k(const float* __restrict__ pbuf, int nsl, int hidden,
                    const float* __restrict__ bias,
                    const float* __restrict__ cprev, long cpbs,
                    float* __restrict__ hout, long hobs,
                    float* __restrict__ cout_, long cobs,
                    float* __restrict__ hout2, long ho2bs, int nb)
{
    const long idx = (long)blockIdx.x * 256 + threadIdx.x;
    if (idx >= (long)nb * hidden * PX) return;
    const long px = idx & 16383;
    const long v = idx >> 14;
    const int hc = (int)(v % hidden), b = (int)(v / hidden);
    const int nco = 4 * hidden;
    float g4[4] = {0.f, 0.f, 0.f, 0.f};
    for (int s = 0; s < nsl; s++)
#pragma unroll
        for (int g = 0; g < 4; g++)
            g4[g] += pbuf[(((long)s * nb + b) * nco + g * hidden + hc) * PX + px];
    const float i_ = sigmoidf_(g4[0] + bias[hc]);
    const float f_ = sigmoidf_(g4[1] + bias[hidden + hc]);
    const float o_ = sigmoidf_(g4[2] + bias[2 * hidden + hc]);
    const float g_ = tanhf(g4[3] + bias[3 * hidden + hc]);
    const float cp = cprev[(long)b * cpbs + (long)hc * PX + px];
    const float c2 = f_ * cp + i_ * g_;
    const float h2 = o_ * tanhf(c2);
    hout[(long)b * hobs + (long)hc * PX + px] = h2;
    cout_[(long)b * cobs + (long)hc * PX + px] = c2;
    if (hout2) hout2[(long)b * ho2bs + (long)hc * PX + px] = h2;
}

// ============ fused input-attention score (phase 1, full batch) ============
__global__ __launch_bounds__(256)
void iattn_k(const float* __restrict__ x, const float* __restrict__ A,
             const float* __restrict__ h, const float* __restrict__ c,
             const float* __restrict__ wa1, const float* __restrict__ ba1,
             const float* __restrict__ wa2, const float* __restrict__ ba2,
             float* __restrict__ score)
{
    __shared__ float xl[12][400];              // 12 ch on 20x20 halo
    __shared__ float zl[32][324];              // conv1 out on 18x18
    const int tid = threadIdx.x;
    const int tileX = (blockIdx.x & 7) << 4, tileY = (blockIdx.x >> 3) << 4;
    const int z = blockIdx.z;
    const int b = z & 7, k = z >> 3;

    float* aT = &zl[0][0];                     // 400-float temp (overwritten later)
    for (int idx = tid; idx < 400; idx += 256) {
        const int r = idx / 20, cc = idx - r * 20;
        const int gy = tileY + r - 2, gx = tileX + cc - 2;
        aT[idx] = ((unsigned)gy < 128u && (unsigned)gx < 128u)
                      ? A[((long)b * 10 + k) * PX + gy * 128 + gx] : 0.f;
    }
    __syncthreads();
    for (int ch = 0; ch < 12; ch++) {
        const float* p = (ch < 10) ? x + (((long)b * 10 + ch) * 10 + k) * PX
                       : (ch == 10) ? h + (long)b * PX : c + (long)b * PX;
        for (int idx = tid; idx < 400; idx += 256) {
            const int r = idx / 20, cc = idx - r * 20;
            const int gy = tileY + r - 2, gx = tileX + cc - 2;
            float v = 0.f;
            if ((unsigned)gy < 128u && (unsigned)gx < 128u) {
                v = p[gy * 128 + gx];
                if (ch < 10) v *= aT[idx];
            }
            xl[ch][idx] = v;
        }
    }
    __syncthreads();
    const int i0 = tid, i1 = tid + 256;
    const int zr0 = i0 / 18, zc0 = i0 - zr0 * 18;
    const int zr1 = (i1 < 324) ? i1 / 18 : 0, zc1 = (i1 < 324) ? i1 - (i1 / 18) * 18 : 0;
    float acc0[32], acc1[32];
#pragma unroll
    for (int co = 0; co < 32; co++) { acc0[co] = 0.f; acc1[co] = 0.f; }
    for (int ci = 0; ci < 12; ci++) {
        float wA[9], wB[9];
#pragma unroll
        for (int dy = 0; dy < 3; dy++)
#pragma unroll
            for (int dx = 0; dx < 3; dx++) {
                wA[dy * 3 + dx] = xl[ci][(zr0 + dy) * 20 + zc0 + dx];
                wB[dy * 3 + dx] = xl[ci][(zr1 + dy) * 20 + zc1 + dx];
            }
#pragma unroll
        for (int co = 0; co < 32; co++) {
            const float* wp = wa1 + ((long)co * 12 + ci) * 9;
            float a0 = acc0[co], a1 = acc1[co];
#pragma unroll
            for (int q = 0; q < 9; q++) { a0 = fmaf(wp[q], wA[q], a0); a1 = fmaf(wp[q], wB[q], a1); }
            acc0[co] = a0; acc1[co] = a1;
        }
    }
    __syncthreads();
    {
        const int gy0 = tileY + zr0 - 1, gx0 = tileX + zc0 - 1;
        const bool in0_ = ((unsigned)gy0 < 128u && (unsigned)gx0 < 128u);
        const int gy1 = tileY + zr1 - 1, gx1 = tileX + zc1 - 1;
        const bool in1_ = (i1 < 324) && ((unsigned)gy1 < 128u && (unsigned)gx1 < 128u);
#pragma unroll
        for (int co = 0; co < 32; co++) {
            zl[co][i0] = in0_ ? tanhf(acc0[co] + ba1[co]) : 0.f;
            if (i1 < 324) zl[co][i1] = in1_ ? tanhf(acc1[co] + ba1[co]) : 0.f;
        }
    }
    __syncthreads();
    const int tx = tid & 15, ty = tid >> 4;
    float a = ba2[0];
    for (int co = 0; co < 32; co++) {
#pragma unroll
        for (int ky = 0; ky < 3; ky++)
#pragma unroll
            for (int kx = 0; kx < 3; kx++)
                a = fmaf(wa2[co * 9 + ky * 3 + kx], zl[co][(ty + ky) * 18 + tx + kx], a);
    }
    score[((long)b * 10 + k) * PX + (long)(tileY + ty) * 128 + tileX + tx] = a;
}

// ============ softmax over 10 (+optional compound into A) ==================
__global__ __launch_bounds__(256)
void softmax_mul_k(const float* __restrict__ s, float* __restrict__ A, int nb, int init)
{
    const long idx = (long)blockIdx.x * 256 + threadIdx.x;
    if (idx >= (long)nb * PX) return;
    const long b = idx >> 14, p = idx & 16383;
    const float* base = s + b * 10 * PX + p;
    float v[10]; float m = -1e30f;
#pragma unroll
    for (int t = 0; t < 10; t++) { v[t] = base[t * PX]; m = fmaxf(m, v[t]); }
    float sum = 0.f;
#pragma unroll
    for (int t = 0; t < 10; t++) { v[t] = expf(v[t] - m); sum += v[t]; }
    const float r = 1.f / sum;
    float* Ab = A + b * 10 * PX + p;
#pragma unroll
    for (int t = 0; t < 10; t++)
        Ab[t * PX] = init ? (v[t] * r) : (Ab[t * PX] * v[t] * r);
}

// ============ decoder attention score (y-part fused with cached Zpart) =====
__global__ __launch_bounds__(256)
void attn_fuse_k(const float* __restrict__ y, long ybs,
                 const float* __restrict__ zpart,      // [slot][b][32][PX]
                 const float* __restrict__ wt1,        // (32,129,3,3); y-ch = 0
                 const float* __restrict__ wt2, const float* __restrict__ bt2,
                 float* __restrict__ score, int nb)
{
    __shared__ float ylds[400];
    __shared__ float zl[32][324];
    const int tid = threadIdx.x;
    const int tileX = (blockIdx.x & 7) << 4, tileY = (blockIdx.x >> 3) << 4;
    const int z = blockIdx.z;
    const int b = z % nb, t = z / nb;

    for (int idx = tid; idx < 400; idx += 256) {
        const int r = idx / 20, c = idx - r * 20;
        const int gy = tileY + r - 2, gx = tileX + c - 2;
        ylds[idx] = ((unsigned)gy < 128u && (unsigned)gx < 128u)
                        ? y[(long)b * ybs + gy * 128 + gx] : 0.f;
    }
    __syncthreads();
    const float* zp0 = zpart + ((long)t * nb + b) * 32 * PX;
    for (int idx = tid; idx < 324; idx += 256) {
        const int zr = idx / 18, zc = idx - zr * 18;
        const int gy = tileY + zr - 1, gx = tileX + zc - 1;
        if ((unsigned)gy < 128u && (unsigned)gx < 128u) {
            float yw[9];
#pragma unroll
            for (int dy = 0; dy < 3; dy++)
#pragma unroll
                for (int dx = 0; dx < 3; dx++)
                    yw[dy * 3 + dx] = ylds[(zr + dy) * 20 + zc + dx];
            const long pix = (long)gy * 128 + gx;
#pragma unroll 8
            for (int ch = 0; ch < 32; ch++) {
                const float* wy = wt1 + (long)ch * 129 * 9;
                float s = zp0[(long)ch * PX + pix];
#pragma unroll
                for (int q = 0; q < 9; q++) s = fmaf(wy[q], yw[q], s);
                zl[ch][idx] = tanhf(s);
            }
        } else {
#pragma unroll 8
            for (int ch = 0; ch < 32; ch++) zl[ch][idx] = 0.f;
        }
    }
    __syncthreads();
    const int tx = tid & 15, ty = tid >> 4;
    float a = bt2[0];
    for (int ch = 0; ch < 32; ch++) {
#pragma unroll
        for (int ky = 0; ky < 3; ky++)
#pragma unroll
            for (int kx = 0; kx < 3; kx++)
                a = fmaf(wt2[ch * 9 + ky * 3 + kx], zl[ch][(ty + ky) * 18 + tx + kx], a);
    }
    score[((long)b * 10 + t) * PX + (long)(tileY + ty) * 128 + tileX + tx] = a;
}

// ============ fused softmax + temporal weighted sum, ch-group split ========
// grid: ((nb*PX+255)/256, 8); blockIdx.y = group of 8 channels
__global__ __launch_bounds__(256)
void smax_wsum_k(const float* __restrict__ score, const float* __restrict__ hs1,
                 float* __restrict__ aht, int nb)
{
    const long idx = (long)blockIdx.x * 256 + threadIdx.x;
    if (idx >= (long)nb * PX) return;
    const long b = idx >> 14, p = idx & 16383;
    const int ch0 = blockIdx.y * 8;
    const float* base = score + b * 10 * PX + p;
    float v[10]; float m = -1e30f;
#pragma unroll
    for (int t = 0; t < 10; t++) { v[t] = base[t * PX]; m = fmaxf(m, v[t]); }
    float sum = 0.f;
#pragma unroll
    for (int t = 0; t < 10; t++) { v[t] = expf(v[t] - m); sum += v[t]; }
    const float r = 1.f / sum;
#pragma unroll
    for (int t = 0; t < 10; t++) v[t] *= r;
    const long slot1 = (long)nb * 64 * PX;
#pragma unroll
    for (int j = 0; j < 8; j++) {
        const int ch = ch0 + j;
        float a = 0.f;
#pragma unroll
        for (int t = 0; t < 10; t++)
            a += v[t] * hs1[t * slot1 + (b * 64 + ch) * PX + p];
        aht[(b * 64 + ch) * PX + p] = a;
    }
}

// ---------------------------------------------------------------------------
extern "C" void kernel_launch(void* const* d_in, const int* in_sizes, int n_in,
                              void* d_out, int out_size, void* d_ws, size_t ws_size,
                              hipStream_t stream)
{
    const float* x      = (const float*)d_in[0];
    const float* h0     = (const float*)d_in[1];
    const float* c0in   = (const float*)d_in[2];
    const float* h1     = (const float*)d_in[3];
    const float* c1     = (const float*)d_in[4];
    const float* w_enc0 = (const float*)d_in[5];
    const float* b_enc0 = (const float*)d_in[6];
    const float* w_enc1 = (const float*)d_in[7];
    const float* b_enc1 = (const float*)d_in[8];
    const float* w_dec0 = (const float*)d_in[9];
    const float* b_dec0 = (const float*)d_in[10];
    const float* w_dec1 = (const float*)d_in[11];
    const float* b_dec1 = (const float*)d_in[12];
    const float* wa1 = (const float*)d_in[13];
    const float* ba1 = (const float*)d_in[14];
    const float* wa2 = (const float*)d_in[15];
    const float* ba2 = (const float*)d_in[16];
    const float* wt1 = (const float*)d_in[17];
    const float* bt1 = (const float*)d_in[18];
    const float* wt2 = (const float*)d_in[19];
    const float* bt2 = (const float*)d_in[20];
    float* out = (float*)d_out;

    // ---- adaptive batch tile for phase 2: need = (160 + 1316*nb)*PX*4 B ----
    int nb = 0;
    for (int cand = 8; cand >= 1; cand >>= 1) {
        const size_t need = (size_t)(160 + 1316 * cand) * PX * sizeof(float);
        if (need <= ws_size) { nb = cand; break; }
    }
    if (nb == 0) return;

    float* ws = (float*)d_ws;
    float* hs0 = ws;                      // [10][8][PX]
    float* cs0 = hs0 + 80 * PX;           // [10][8][PX]
    float* G   = cs0 + 80 * PX;
    // phase-1 aliases inside G
    float* A    = G;                      // [8][10][PX]
    float* sc1  = G + 80 * PX;            // [8][10][PX]
    float* pb0  = G + 160 * PX;           // [1][8][4][PX]
    // phase-2 per-group layout inside G
    const long slot1  = (long)nb * 64 * PX;          // hs1 per-t slot
    float* hs1   = G;                                 // 10 * slot1
    float* cs1   = hs1 + 10 * slot1;                  // 2 * slot1 (ping-pong)
    float* zpart = cs1 + 2 * slot1;                   // [10][nb][32][PX]
    float* aht   = zpart + (long)10 * nb * 32 * PX;   // [nb][64][PX]
    float* zpp   = aht + (long)nb * 64 * PX;          // [4][nb][32][PX]
    float* l1p   = zpp + (long)4 * nb * 32 * PX;      // [4][nb][4][PX]
    float* hs0g  = l1p + (long)4 * nb * 4 * PX;       // [5][nb][PX]
    float* cs0g  = hs0g + (long)5 * nb * PX;          // [5][nb][PX]
    float* scD   = cs0g + (long)5 * nb * PX;          // [nb][10][PX]

    const dim3 blk(256);
    const long TDP = (long)T_ * D_ * PX;
    const long zslot = (long)nb * 32 * PX;

    // ================= phase 1: encoder layer 0, FULL batch =================
    for (int t = 0; t < 10; t++) {
        const float* hprev = (t == 0) ? h0 : hs0 + (long)(t - 1) * 8 * PX;
        const float* cprev = (t == 0) ? c0in : cs0 + (long)(t - 1) * 8 * PX;
        iattn_k<<<dim3(64, 1, 80), blk, 0, stream>>>(
            x, A, hprev, cprev, wa1, ba1, wa2, ba2, sc1);
        softmax_mul_k<<<512, blk, 0, stream>>>(sc1, A, 8, t == 0);
        convp_k<4><<<dim3(64, 1, 8), blk, 0, stream>>>(
            x + (long)t * D_ * PX, 10, TDP, PX,
            hprev, PX, PX,
            A, 10 * PX, PX,
            w_enc0, 11, 0,
            make_int4(0, 0, 0, 0), make_int4(11, 0, 0, 0),
            pb0, 4, 8);
        combine_lstm_k<<<512, blk, 0, stream>>>(
            pb0, 1, 1, b_enc0, cprev, PX,
            hs0 + (long)t * 8 * PX, PX,
            cs0 + (long)t * 8 * PX, PX,
            (float*)nullptr, 0, 8);
    }

    // ================= phase 2: per batch-group =================
    for (int b0 = 0; b0 < 8; b0 += nb) {
        const float* xb  = x + (long)b0 * TDP;
        const float* h1b = h1 + (long)b0 * 64 * PX;
        const float* c1b = c1 + (long)b0 * 64 * PX;
        float* outb = out + (long)b0 * 5 * PX;

        // -------- encoder layer 1 + incremental Zpart --------
        for (int t = 0; t < 10; t++) {
            const float* hprev = (t == 0) ? h1b : hs1 + (long)(t - 1) * slot1;
            const float* cprev = (t == 0) ? c1b : cs1 + (long)((t + 1) & 1) * slot1;
            conv_lstm_k<<<dim3(16, 32, nb), blk, 0, stream>>>(
                hs0 + (long)t * 8 * PX + (long)b0 * PX, 1, PX, PX,
                hprev, 64, 64 * PX, PX,
                w_enc1, b_enc1, 64, cprev, 64 * PX,
                hs1 + (long)t * slot1, 64 * PX,
                cs1 + (long)(t & 1) * slot1, 64 * PX);
            convp_k<8><<<dim3(64, 4, 4 * nb), blk, 0, stream>>>(
                hs1 + (long)t * slot1, 64, 64 * PX, PX,
                cs1 + (long)(t & 1) * slot1, 64 * PX, PX,
                nullptr, 0, 0,
                wt1, 129, 1,
                make_int4(0, 32, 64, 96), make_int4(32, 32, 32, 32),
                zpp, 32, nb);
            combine_add_k<<<(int)(((long)nb * 32 * PX + 255) / 256), blk, 0, stream>>>(
                zpp, 4, 32, bt1, zpart + (long)t * zslot, nb);
        }

        // -------- decoder (5 steps) --------
        for (int s = 0; s < 5; s++) {
            const float* yptr; long ybs;
            if (s == 0) { yptr = xb + 9L * D_ * PX; ybs = TDP; }
            else        { yptr = hs0g + (long)(s - 1) * nb * PX; ybs = PX; }
            const float* hb1 = (s == 0) ? hs0 + 9L * 8 * PX + (long)b0 * PX
                                        : hs0g + (long)(s - 1) * nb * PX;
            const float* cb1 = (s == 0) ? cs0 + 9L * 8 * PX + (long)b0 * PX
                                        : cs0g + (long)(s - 1) * nb * PX;

            attn_fuse_k<<<dim3(64, 1, 10 * nb), blk, 0, stream>>>(
                yptr, ybs, zpart, wt1, wt2, bt2, scD, nb);
            smax_wsum_k<<<dim3((int)(((long)nb * PX + 255) / 256), 8), blk, 0, stream>>>(
                scD, hs1, aht, nb);

            // decoder LSTM 0: in = [y(1); aht(64)], c = cs1[(s+1)&1]
            conv_lstm_k<<<dim3(16, 32, nb), blk, 0, stream>>>(
                yptr, 1, ybs, PX, aht, 64, 64 * PX, PX,
                w_dec0, b_dec0, 64,
                cs1 + (long)((s + 1) & 1) * slot1, 64 * PX,
                hs1 + (long)s * slot1, 64 * PX,
                cs1 + (long)(s & 1) * slot1, 64 * PX);

            // decoder LSTM 1 (split-K): in = [ht(64); hb1(1)]
            convp_k<4><<<dim3(64, 1, 4 * nb), blk, 0, stream>>>(
                hs1 + (long)s * slot1, 64, 64 * PX, PX,
                hb1, PX, PX,
                nullptr, 0, 0,
                w_dec1, 65, 0,
                make_int4(0, 17, 33, 49), make_int4(17, 16, 16, 16),
                l1p, 4, nb);
            combine_lstm_k<<<(int)(((long)nb * PX + 255) / 256), blk, 0, stream>>>(
                l1p, 4, 1, b_dec1, cb1, PX,
                hs0g + (long)s * nb * PX, PX,
                cs0g + (long)s * nb * PX, PX,
                outb + (long)s * PX, 5 * PX, nb);

            // Zpart update for rewritten slot s (skip last step)
            if (s < 4) {
                convp_k<8><<<dim3(64, 4, 4 * nb), blk, 0, stream>>>(
                    hs1 + (long)s * slot1, 64, 64 * PX, PX,
                    cs1 + (long)(s & 1) * slot1, 64 * PX, PX,
                    nullptr, 0, 0,
                    wt1, 129, 1,
                    make_int4(0, 32, 64, 96), make_int4(32, 32, 32, 32),
                    zpp, 32, nb);
                combine_add_k<<<(int)(((long)nb * 32 * PX + 255) / 256), blk, 0, stream>>>(
                    zpp, 4, 32, bt1, zpart + (long)s * zslot, nb);
            }
        }
    }
}